// Round 6
// baseline (487.678 us; speedup 1.0000x reference)
//
#include <hip/hip_runtime.h>

#define T_SEQ 2048

typedef __bf16 bf16x8 __attribute__((ext_vector_type(8)));
typedef float f32x4 __attribute__((ext_vector_type(4)));
typedef unsigned short u16;

__device__ __forceinline__ u16 f2b(float f) {
  unsigned u = __float_as_uint(f);
  unsigned r = 0x7fffu + ((u >> 16) & 1u);
  return (u16)((u + r) >> 16);
}
__device__ __forceinline__ float b2f(u16 v) {
  return __uint_as_float(((unsigned)v) << 16);
}
__device__ __forceinline__ f32x4 mfma16(bf16x8 a, bf16x8 b, f32x4 c) {
  return __builtin_amdgcn_mfma_f32_16x16x32_bf16(a, b, c, 0, 0, 0);
}
// pack two f32 -> two bf16 (RTZ) in ONE v_perm_b32 (truncation ~ bf16 noise).
__device__ __forceinline__ unsigned pkhi(float lo, float hi) {
  return __builtin_amdgcn_perm(__float_as_uint(hi), __float_as_uint(lo), 0x07060302u);
}
// raw exp2 (no OCML denormal fixup; -1e30 underflows to 0 which is what we want)
#if defined(__has_builtin)
#if __has_builtin(__builtin_amdgcn_exp2f)
#define HAVE_RAW_EXP2 1
#endif
#endif
__device__ __forceinline__ float exp2r(float x) {
#ifdef HAVE_RAW_EXP2
  return __builtin_amdgcn_exp2f(x);
#else
  float r;
  asm("v_exp_f32 %0, %1" : "=v"(r) : "v"(x));
  return r;
#endif
}
// async global->LDS, 16B per lane; LDS dest = wave-uniform base + lane*16
__device__ __forceinline__ void glds16(const void* g, void* s) {
  __builtin_amdgcn_global_load_lds(
      (const __attribute__((address_space(1))) void*)(uintptr_t)g,
      (__attribute__((address_space(3))) void*)(unsigned)(uintptr_t)s, 16, 0, 0);
}

// ---------------- lambda scalar ----------------
__global__ void lam_kernel(const float* __restrict__ q1, const float* __restrict__ k1,
                           const float* __restrict__ q2, const float* __restrict__ k2,
                           float* __restrict__ outp) {
  int l = threadIdx.x;
  float a = q1[l] * k1[l];
  float c = q2[l] * k2[l];
  #pragma unroll
  for (int off = 32; off > 0; off >>= 1) {
    a += __shfl_down(a, off);
    c += __shfl_down(c, off);
  }
  if (l == 0) outp[0] = expf(a) - expf(c) + 0.7836057665316244f;  // + LAMBDA_INIT
}

// ---------------- fp32 -> bf16 convert ----------------
__global__ __launch_bounds__(256) void convert_kernel(const float* __restrict__ in,
                                                      u16* __restrict__ outp, int n) {
  int i = (blockIdx.x * 256 + threadIdx.x) * 4;
  if (i >= n) return;
  float4 v = *(const float4*)(in + i);
  ushort4 pk;
  pk.x = f2b(v.x); pk.y = f2b(v.y); pk.z = f2b(v.z); pk.w = f2b(v.w);
  *(ushort4*)(outp + i) = pk;
}

// ---------------- fused W transpose: Wq/Wk/Wv/Wo fp32 -> bf16 WT[6144][2048] ----------------
// rows 0..2048 = Wq^T, 2048..3072 = Wk^T, 3072..4096 = Wv^T, 4096..6144 = Wo^T
__global__ __launch_bounds__(256) void transposeW_kernel(const float* __restrict__ Wq,
                                                         const float* __restrict__ Wk,
                                                         const float* __restrict__ Wv,
                                                         const float* __restrict__ Wo,
                                                         u16* __restrict__ outp) {
  __shared__ float tile[32][33];
  const int ro0 = blockIdx.y * 32;  // out-row base (0..6144), never crosses a segment
  const int r0 = blockIdx.x * 32;   // source-row base (0..2048)
  const float* src; int C, cbase;
  if (ro0 < 2048)      { src = Wq; C = 2048; cbase = 0; }
  else if (ro0 < 3072) { src = Wk; C = 1024; cbase = 2048; }
  else if (ro0 < 4096) { src = Wv; C = 1024; cbase = 3072; }
  else                 { src = Wo; C = 2048; cbase = 4096; }
  const int cs0 = ro0 - cbase;
  const int tx = threadIdx.x & 31, ty = threadIdx.x >> 5;
  #pragma unroll
  for (int k2 = 0; k2 < 4; k2++)
    tile[ty * 4 + k2][tx] = src[(size_t)(r0 + ty * 4 + k2) * C + cs0 + tx];
  __syncthreads();
  #pragma unroll
  for (int k2 = 0; k2 < 4; k2++)
    outp[(size_t)(ro0 + ty * 4 + k2) * 2048 + r0 + tx] = f2b(tile[tx][ty * 4 + k2]);
}

// ---------------- m97-style GEMM: C[M][N] = A[M][K] @ BT[N][K]^T (kept for out-proj) --------
template <bool OUT_BF16>
__global__ __launch_bounds__(256) void gemm128_kernel(const u16* __restrict__ A,
                                                      const u16* __restrict__ BT,
                                                      void* __restrict__ C, int N, int K) {
  __shared__ alignas(16) u16 As[128 * 64];
  __shared__ alignas(16) u16 Bs[128 * 64];
  const int tid = threadIdx.x, w = tid >> 6, lane = tid & 63;
  const int l15 = lane & 15, quad = lane >> 4;
  const int m0 = blockIdx.y * 128, n0 = blockIdx.x * 128;
  const int wm = (w >> 1) * 64, wn = (w & 1) * 64;
  const int lr = lane >> 3, slot = lane & 7, csw = slot ^ lr;
  f32x4 acc[4][4];
  #pragma unroll
  for (int mt = 0; mt < 4; mt++)
    #pragma unroll
    for (int nt = 0; nt < 4; nt++) acc[mt][nt] = (f32x4){0.f, 0.f, 0.f, 0.f};
  const u16* Ag = A + (size_t)(m0 + w * 32 + lr) * K + csw * 8;
  const u16* Bg = BT + (size_t)(n0 + w * 32 + lr) * K + csw * 8;
  u16* Asd = As + (w * 32) * 64;
  u16* Bsd = Bs + (w * 32) * 64;
  for (int kt = 0; kt < K; kt += 64) {
    #pragma unroll
    for (int i = 0; i < 4; i++) {
      glds16(Ag + kt + (size_t)(i * 8) * K, Asd + i * 512);
      glds16(Bg + kt + (size_t)(i * 8) * K, Bsd + i * 512);
    }
    __syncthreads();
    #pragma unroll
    for (int kk = 0; kk < 2; kk++) {
      bf16x8 am[4], bn[4];
      #pragma unroll
      for (int t = 0; t < 4; t++) {
        const int ra = wm + t * 16 + l15;
        am[t] = *(const bf16x8*)&As[ra * 64 + (((kk * 4 + quad) ^ (ra & 7)) << 3)];
        const int rb = wn + t * 16 + l15;
        bn[t] = *(const bf16x8*)&Bs[rb * 64 + (((kk * 4 + quad) ^ (rb & 7)) << 3)];
      }
      #pragma unroll
      for (int mt = 0; mt < 4; mt++)
        #pragma unroll
        for (int nt = 0; nt < 4; nt++) acc[mt][nt] = mfma16(am[mt], bn[nt], acc[mt][nt]);
    }
    __syncthreads();
  }
  const int row = m0 + wm + quad * 4;
  #pragma unroll
  for (int mt = 0; mt < 4; mt++) {
    #pragma unroll
    for (int nt = 0; nt < 4; nt++) {
      const int col = n0 + wn + nt * 16 + l15;
      #pragma unroll
      for (int rr = 0; rr < 4; rr++) {
        if (OUT_BF16)
          ((u16*)C)[(size_t)(row + mt * 16 + rr) * N + col] = f2b(acc[mt][nt][rr]);
        else
          ((float*)C)[(size_t)(row + mt * 16 + rr) * N + col] = acc[mt][nt][rr];
      }
    }
  }
}

// ---------------- 256x256 8-phase GEMM (T2+T3+T4+T5): C[M][N] = A[M][K] @ BT[N][K]^T --------
// 512 thr = 8 waves (2M x 4N, 16-interleaved). BK=64, 2x double-buffered LDS (128 KiB).
// Staging runs 7 half-tiles ahead (half = 128 rows x 64, 2 glds); per tile order A0,B0,B1,A1.
// vmcnt(6) only at phases 4/8: drains to "all but last 3 halves landed" = exactly the halves
// the next tile's ds_reads need (min stage->read gap is 6 phases). Never vmcnt(0) in-loop.
// Chunk swizzle identical to gemm128 (pre-swizzled source csw = slot^lr; read ^ (row&7)).
#define STAGE_HALF(TILE, ROLE, BUF)                                                     \
  do {                                                                                  \
    const u16* sp_ = ((ROLE) == 0 || (ROLE) == 3 ? Ag : Bg) +                           \
                     (size_t)((ROLE) >= 2 ? 128 : 0) * K + (size_t)(TILE) * 64;         \
    u16* dp_ = ((ROLE) == 0 || (ROLE) == 3 ? &As[BUF][0] : &Bs[BUF][0]) +               \
               (((ROLE) >= 2 ? 128 : 0) + w * 8) * 64;                                  \
    glds16(sp_, dp_);                                                                   \
    glds16(sp_ + (size_t)64 * K, dp_ + 4096);                                           \
  } while (0)

#define PHASE(I, J, BUF, NEWA, NEWB, BN, STILE, SROLE, SBUF, DOVM)                      \
  do {                                                                                  \
    if (NEWA) {                                                                         \
      _Pragma("unroll") for (int u_ = 0; u_ < 4; u_++) {                                \
        const int ar_ = ((I) * 4 + u_) * 32 + wm * 16 + l15;                            \
        _Pragma("unroll") for (int kk_ = 0; kk_ < 2; kk_++)                             \
            am[u_][kk_] = *(const bf16x8*)&As[BUF][ar_ * 64 +                           \
                              (((kk_ * 4 + quad) ^ (ar_ & 7)) << 3)];                   \
      }                                                                                 \
    }                                                                                   \
    if (NEWB) {                                                                         \
      _Pragma("unroll") for (int v_ = 0; v_ < 2; v_++) {                                \
        const int br_ = ((J) * 2 + v_) * 64 + wn * 16 + l15;                            \
        _Pragma("unroll") for (int kk_ = 0; kk_ < 2; kk_++)                             \
            BN[v_][kk_] = *(const bf16x8*)&Bs[BUF][br_ * 64 +                           \
                              (((kk_ * 4 + quad) ^ (br_ & 7)) << 3)];                   \
      }                                                                                 \
    }                                                                                   \
    STAGE_HALF(STILE, SROLE, SBUF);                                                     \
    __builtin_amdgcn_s_barrier();                                                       \
    asm volatile("s_waitcnt lgkmcnt(0)" ::: "memory");                                  \
    __builtin_amdgcn_sched_barrier(0);                                                  \
    __builtin_amdgcn_s_setprio(1);                                                      \
    _Pragma("unroll") for (int u_ = 0; u_ < 4; u_++)                                    \
        _Pragma("unroll") for (int v_ = 0; v_ < 2; v_++) {                              \
      acc[(I) * 4 + u_][(J) * 2 + v_] =                                                 \
          mfma16(am[u_][0], BN[v_][0], acc[(I) * 4 + u_][(J) * 2 + v_]);                \
      acc[(I) * 4 + u_][(J) * 2 + v_] =                                                 \
          mfma16(am[u_][1], BN[v_][1], acc[(I) * 4 + u_][(J) * 2 + v_]);                \
    }                                                                                   \
    __builtin_amdgcn_s_setprio(0);                                                      \
    if (DOVM) asm volatile("s_waitcnt vmcnt(6)" ::: "memory");                          \
    __builtin_amdgcn_s_barrier();                                                       \
  } while (0)

__global__ __launch_bounds__(512, 2) void gemm256_kernel(const u16* __restrict__ A,
                                                         const u16* __restrict__ BT,
                                                         u16* __restrict__ C, int N, int K) {
  __shared__ alignas(16) u16 As[2][256 * 64];
  __shared__ alignas(16) u16 Bs[2][256 * 64];
  const int tid = threadIdx.x, w = tid >> 6, lane = tid & 63;
  const int l15 = lane & 15, quad = lane >> 4;
  const int wm = w >> 2, wn = w & 3;
  const int lr = lane >> 3, slot = lane & 7, csw = slot ^ lr;
  const int m0 = blockIdx.y * 256, n0 = blockIdx.x * 256;
  const int nkt = K >> 6;  // must be even

  f32x4 acc[8][4];
  #pragma unroll
  for (int r = 0; r < 8; r++)
    #pragma unroll
    for (int s = 0; s < 4; s++) acc[r][s] = (f32x4){0.f, 0.f, 0.f, 0.f};

  const u16* Ag = A + (size_t)(m0 + w * 8 + lr) * K + csw * 8;
  const u16* Bg = BT + (size_t)(n0 + w * 8 + lr) * K + csw * 8;

  bf16x8 am[4][2], bn0[2][2], bn1[2][2];

  // prologue: tile0 (A0,B0,B1,A1) + tile1 (A0,B0,B1); land tile0, keep 3 halves in flight
  STAGE_HALF(0, 0, 0); STAGE_HALF(0, 1, 0); STAGE_HALF(0, 2, 0); STAGE_HALF(0, 3, 0);
  STAGE_HALF(1, 0, 1); STAGE_HALF(1, 1, 1); STAGE_HALF(1, 2, 1);
  asm volatile("s_waitcnt vmcnt(6)" ::: "memory");
  __builtin_amdgcn_s_barrier();

  #pragma unroll 1
  for (int t = 0; t < nkt; t += 2) {
    // tile t (buf0): quads (0,0) (0,1) (1,0) (1,1); stage g = 4t+7+k
    PHASE(0, 0, 0, 1, 1, bn0, t + 1, 3, 1, 0);
    PHASE(0, 1, 0, 0, 1, bn1, t + 2, 0, 0, 0);
    PHASE(1, 0, 0, 1, 0, bn0, t + 2, 1, 0, 0);
    PHASE(1, 1, 0, 0, 0, bn1, t + 2, 2, 0, 1);
    // tile t+1 (buf1)
    PHASE(0, 0, 1, 1, 1, bn0, t + 2, 3, 0, 0);
    PHASE(0, 1, 1, 0, 1, bn1, t + 3, 0, 1, 0);
    PHASE(1, 0, 1, 1, 0, bn0, t + 3, 1, 1, 0);
    PHASE(1, 1, 1, 0, 0, bn1, t + 3, 2, 1, 1);
    // overrun stages (last iters) hit tiles >= nkt: reads stay inside the workspace and
    // only overwrite already-consumed LDS halves -> harmless, no guard needed.
  }

  const int crow = m0 + wm * 16 + quad * 4;
  const int ccol = n0 + wn * 16 + l15;
  #pragma unroll
  for (int r = 0; r < 8; r++)
    #pragma unroll
    for (int s = 0; s < 4; s++)
      #pragma unroll
      for (int rr = 0; rr < 4; rr++)
        C[(size_t)(crow + r * 32 + rr) * N + ccol + s * 64] = f2b(acc[r][s][rr]);
}

// ---------------- merged rotary: QKV -> Qb (heads 0..31, *qscale) and Kb (heads 32..47) ------
__global__ __launch_bounds__(256) void rotary_kernel(const u16* __restrict__ qkv,
                                                     u16* __restrict__ Qb,
                                                     u16* __restrict__ Kb, float qscale) {
  int idx = blockIdx.x * 256 + threadIdx.x;
  int i = idx & 31;
  int bt = (idx >> 5) & 4095;
  int hh = idx >> 17;  // 0..47 (wave-uniform)
  int t = bt & (T_SEQ - 1), b = bt >> 11;
  bool isq = hh < 32;
  int col = isq ? hh * 64 : 2048 + (hh - 32) * 64;
  size_t inb = (size_t)bt * 4096 + col + i;
  float x1 = b2f(qkv[inb]);
  float x2 = b2f(qkv[inb + 32]);
  float invf = exp2f(-(float)i * 0.4152410118609203f);
  float ang = (float)t * invf;
  float c = cosf(ang), s = sinf(ang);
  float scale = isq ? qscale : 1.0f;
  float o1 = (x1 * c + x2 * s) * scale;
  float o2 = (x2 * c - x1 * s) * scale;
  u16* outp = isq ? (Qb + (size_t)(b * 32 + hh) * (T_SEQ * 64))
                  : (Kb + (size_t)(b * 16 + hh - 32) * (T_SEQ * 64));
  size_t ob = (size_t)t * 64 + i;
  outp[ob] = f2b(o1);
  outp[ob + 32] = f2b(o2);
}

// ---------------- V slice transpose: QKV cols [3072..4096) -> Vt[B][8][32 stile][128][64] ----
// s-axis PERMUTED inside each 64-tile so the PV B-operand (P^T fragment) is lane-local:
// logical col p = hb*32 + ((s>>2)&3)*8 + ((s>>4)&1)*4 + (s&3), hb = s>>5.
// Then MFMA k=(quad*8+i) of vf0/vf1 reads s = kk*32 + (i>>2)*16 + quad*4 + (i&3), which is
// exactly the S^T output layout p[j][rr] (s = j*16 + quad*4 + rr) -> zero cross-lane traffic.
__global__ __launch_bounds__(256) void vtrans_kernel(const u16* __restrict__ qkv,
                                                     u16* __restrict__ outp) {
  __shared__ unsigned tile[32][33];
  int bh = blockIdx.z;  // b*8+hv
  int t0 = blockIdx.x * 32, dv0 = blockIdx.y * 32;
  int tx = threadIdx.x & 31, ty = threadIdx.x >> 5;
  int bt_base = (bh >> 3) * T_SEQ;
  int col = 3072 + (bh & 7) * 128 + dv0 + tx;
  #pragma unroll
  for (int k2 = 0; k2 < 4; k2++)
    tile[ty * 4 + k2][tx] = qkv[(size_t)(bt_base + t0 + ty * 4 + k2) * 4096 + col];
  __syncthreads();
  const int stile = t0 >> 6;
  const int sold = (t0 & 63) + tx;
  const int slo = sold & 31, hb = sold >> 5;
  const int sp = hb * 32 + ((slo >> 2) & 3) * 8 + ((slo >> 4) & 1) * 4 + (slo & 3);
  #pragma unroll
  for (int k2 = 0; k2 < 4; k2++) {
    int dv = dv0 + ty * 4 + k2;
    outp[(((size_t)bh * 32 + stile) * 128 + dv) * 64 + sp] = (u16)tile[tx][ty * 4 + k2];
  }
}

// ---------------- flash diff-attention, 8-wave 128-q blocks, counted-vmcnt pipeline --------
// Qb [B][32][T][64] (rotary, *HD^-.5*log2e), Kb [B][16][T][64], Vt [B][8][32][128][64 perm]
// S^T = K·Q^T (lane: q=l15, s=quad*4+rr); O^T = V^T·P^T. P stays IN REGISTERS.
// Block = 512 thr = 8 waves, each owning 16 q rows -> 128 q (q-tile pair 2a, 2a+1) share ONE
// K/V staging stream (staged tiles per bh: 528 -> 272; waves/CU: 8 -> 16 at 2 blocks/CU).
// Per step each wave stages 3 glds16 (K: rows [8w,8w+8); V: d-rows [16w,16w+16)).
// T4: issue prefetch(st+1) -> vmcnt(3) (waits for prefetch(st)) -> barrier -> compute -> barrier.
// Grid 1-D 512 decoded so id and id+256 have complementary costs (sum 34) -> balanced CUs.
// Low-tile waves (w<4) overshoot 1 step at st=2a+1: fully masked -> exact zeros, no branch.
__global__ __launch_bounds__(512, 4) void attn_kernel(const u16* __restrict__ Qb,
                                                      const u16* __restrict__ Kb,
                                                      const u16* __restrict__ Vt,
                                                      const float* __restrict__ lamp,
                                                      const float* __restrict__ g,
                                                      u16* __restrict__ attn_out) {
  __shared__ alignas(16) char smem[49152];
  u16* const Ks0 = (u16*)smem;              // [2][64*64], XOR-swizzled, double-buffered
  u16* const Vs0 = (u16*)(smem + 16384);    // [2][128*64], XOR-swizzled, double-buffered
  u16* const Psb = (u16*)smem;              // [8][16][136] epilogue-only (aliases Ks/Vs)
  const int id = blockIdx.x;
  const int araw = id & 15;
  const int bh = (id >> 4) & 31;
  const int a = (id < 256) ? 15 - araw : araw;  // q-pair index; id & id+256 complement
  const int b = bh >> 4, h = bh & 15;
  const int tid = threadIdx.x, w = tid >> 6, lane = tid & 63;
  const int l15 = lane & 15, quad = lane >> 4;
  const int lr = lane >> 3, slot = lane & 7, csw = slot ^ lr;
  const float lam = lamp[0];

  const int tlast = 2 * a + 1;            // last s-tile this block touches
  const int myTile = 2 * a + (w >> 2);    // wave's own diagonal s-tile
  const int qb = a * 128 + w * 16;        // wave's first q row
  const int qglob = qb + l15;             // this lane's q row

  // per-lane global staging bases (tile-contiguous: K tile = 4096 u16, V tile = 8192 u16)
  // wave w stages K rows [8w,8w+8) (1 glds) and V d-rows [16w,16w+16) (2 glds)
  const u16* Kg = Kb + (size_t)(b * 16 + h) * (T_SEQ * 64) + (w * 8 + lr) * 64 + csw * 8;
  const u16* Vg = Vt + (size_t)(b * 8 + (h >> 1)) * (T_SEQ * 128) + w * 1024 + lr * 64 + csw * 8;
  u16* kd[2] = {Ks0 + w * 512, Ks0 + 4096 + w * 512};
  u16* vd[2] = {Vs0 + w * 1024, Vs0 + 8192 + w * 1024};

  bf16x8 qf[2][2];
  #pragma unroll
  for (int e = 0; e < 2; e++)
    #pragma unroll
    for (int kk = 0; kk < 2; kk++)
      qf[e][kk] = *(const bf16x8*)&Qb[((size_t)(b * 32 + 2 * h + e) * T_SEQ + qb + l15) * 64 +
                                      kk * 32 + quad * 8];

  f32x4 o[2][8];
  float lsum[2] = {0.f, 0.f};
  #pragma unroll
  for (int e = 0; e < 2; e++)
    #pragma unroll
    for (int nt = 0; nt < 8; nt++) o[e][nt] = (f32x4){0.f, 0.f, 0.f, 0.f};

  // prologue: issue tile 0 into buf 0 (no drain; first loop iter waits via vmcnt(3))
  glds16(Kg, kd[0]);
  glds16(Vg, vd[0]); glds16(Vg + 512, vd[0] + 512);

  #pragma unroll 1
  for (int st = 0; st <= tlast; st++) {
    const int buf = st & 1;
    const u16* Ksb = Ks0 + buf * 4096;
    const u16* Vsb = Vs0 + buf * 8192;
    if (st < tlast) {  // issue prefetch(st+1); then wait only for prefetch(st) (3 newer ok)
      const u16* kp = Kg + (size_t)(st + 1) * 4096;
      const u16* vp = Vg + (size_t)(st + 1) * 8192;
      glds16(kp, kd[buf ^ 1]);
      glds16(vp, vd[buf ^ 1]); glds16(vp + 512, vd[buf ^ 1] + 512);
      asm volatile("s_waitcnt vmcnt(3)" ::: "memory");
    } else {
      asm volatile("s_waitcnt vmcnt(0)" ::: "memory");
    }
    __builtin_amdgcn_s_barrier();  // B1: tile st collectively ready
    __builtin_amdgcn_sched_barrier(0);

    bf16x8 kf[4][2];
    #pragma unroll
    for (int j = 0; j < 4; j++) {
      const int rk = j * 16 + l15;
      #pragma unroll
      for (int kk = 0; kk < 2; kk++)
        kf[j][kk] = *(const bf16x8*)&Ksb[rk * 64 + (((kk * 4 + quad) ^ (rk & 7)) << 3)];
    }

    bf16x8 pa[2][2];
    #pragma unroll
    for (int e = 0; e < 2; e++) {
      f32x4 sc[4];
      __builtin_amdgcn_s_setprio(1);
      #pragma unroll
      for (int j = 0; j < 4; j++) {  // S^T: lane holds s=quad*4+rr, q=l15
        f32x4 z = {0.f, 0.f, 0.f, 0.f};
        z = mfma16(kf[j][0], qf[e][0], z);
        sc[j] = mfma16(kf[j][1], qf[e][1], z);
      }
      __builtin_amdgcn_s_setprio(0);
      if (st >= myTile) {  // causal mask (wave's diagonal tile and beyond)
        #pragma unroll
        for (int j = 0; j < 4; j++) {
          int srow = st * 64 + j * 16 + quad * 4;
          #pragma unroll
          for (int rr = 0; rr < 4; rr++)
            if (srow + rr > qglob) sc[j][rr] = -1e30f;
        }
      }
      float ls = 0.f;
      union { unsigned u[8]; bf16x8 v[2]; } pk;
      #pragma unroll
      for (int j = 0; j < 4; j++) {
        #pragma unroll
        for (int rr = 0; rr < 4; rr++) {
          float p = exp2r(sc[j][rr]);  // log2e folded into Q scale
          sc[j][rr] = p;
          ls += p;
        }
        pk.u[j * 2] = pkhi(sc[j][0], sc[j][1]);
        pk.u[j * 2 + 1] = pkhi(sc[j][2], sc[j][3]);
      }
      // pa[kk][i] = p[2kk + (i>>2)][i&3]; V's s-permutation makes this the exact B-frag
      pa[e][0] = pk.v[0];
      pa[e][1] = pk.v[1];
      lsum[e] += ls;
    }
    __builtin_amdgcn_s_setprio(1);
    #pragma unroll
    for (int nt = 0; nt < 8; nt++) {  // O^T = V^T·P^T
      const int rv = nt * 16 + l15;
      bf16x8 vf0 = *(const bf16x8*)&Vsb[rv * 64 + ((quad ^ (rv & 7)) << 3)];
      bf16x8 vf1 = *(const bf16x8*)&Vsb[rv * 64 + (((4 + quad) ^ (rv & 7)) << 3)];
      o[0][nt] = mfma16(vf0, pa[0][0], o[0][nt]);
      o[0][nt] = mfma16(vf1, pa[0][1], o[0][nt]);
      o[1][nt] = mfma16(vf0, pa[1][0], o[1][nt]);
      o[1][nt] = mfma16(vf1, pa[1][1], o[1][nt]);
    }
    __builtin_amdgcn_s_setprio(0);
    __builtin_amdgcn_s_barrier();  // B2: reads of buf retired -> next step may overwrite
  }

  // lane holds O^T[d = nt*16+quad*4+rr][q = l15]; reduce sums over quads (s-dim)
  float l0 = lsum[0], l1 = lsum[1];
  l0 += __shfl_xor(l0, 16); l0 += __shfl_xor(l0, 32);
  l1 += __shfl_xor(l1, 16); l1 += __shfl_xor(l1, 32);
  const float il0 = 1.f / l0, il1 = lam / l1;
  float ssq = 0.f;
  #pragma unroll
  for (int nt = 0; nt < 8; nt++)
    #pragma unroll
    for (int rr = 0; rr < 4; rr++) {
      float v = o[0][nt][rr] * il0 - o[1][nt][rr] * il1;
      o[0][nt][rr] = v;
      ssq += v * v;
    }
  ssq += __shfl_xor(ssq, 16);
  ssq += __shfl_xor(ssq, 32);
  const float rsc = rsqrtf(ssq * (1.f / 128.f) + 1e-6f) * 0.2163942334683756f;
  // stage normalized rows to LDS (transpose back): Ps[q=l15][d = 0..127]
  // (Psb aliases Ks/Vs; all in-loop LDS reads retired at B2 of the final step)
  #pragma unroll
  for (int nt = 0; nt < 8; nt++) {
    float4 gv = *(const float4*)&g[nt * 16 + quad * 4];
    uint2 pk;
    pk.x = (unsigned)f2b(o[0][nt][0] * rsc * gv.x) |
           ((unsigned)f2b(o[0][nt][1] * rsc * gv.y) << 16);
    pk.y = (unsigned)f2b(o[0][nt][2] * rsc * gv.z) |
           ((unsigned)f2b(o[0][nt][3] * rsc * gv.w) << 16);
    *(uint2*)&Psb[(w * 16 + l15) * 136 + nt * 16 + quad * 4] = pk;
  }
  asm volatile("s_waitcnt lgkmcnt(0)" ::: "memory");
  __builtin_amdgcn_sched_barrier(0);
  // full-coverage read-back: 4 iters x 64 lanes x 8 u16 = 2048 = 16 rows x 128 cols per wave
  #pragma unroll
  for (int i = 0; i < 4; i++) {
    const int r = (lane >> 4) + i * 4, c = (lane & 15) * 8;
    bf16x8 ov = *(const bf16x8*)&Psb[(w * 16 + r) * 136 + c];
    *(bf16x8*)&attn_out[(size_t)(b * T_SEQ + qb + r) * 2048 + h * 128 + c] = ov;
  }
}

extern "C" void kernel_launch(void* const* d_in, const int* in_sizes, int n_in, void* d_out,
                              int out_size, void* d_ws, size_t ws_size, hipStream_t stream) {
  const float* x = (const float*)d_in[0];
  const float* Wq = (const float*)d_in[1];
  const float* Wk = (const float*)d_in[2];
  const float* Wv = (const float*)d_in[3];
  const float* Wo = (const float*)d_in[4];
  const float* lq1 = (const float*)d_in[5];
  const float* lk1 = (const float*)d_in[6];
  const float* lq2 = (const float*)d_in[7];
  const float* lk2 = (const float*)d_in[8];
  const float* g = (const float*)d_in[9];

  char* ws = (char*)d_ws;
  u16* WT = (u16*)(ws);                 // [6144][2048]: WqT;WkT;WvT;WoT, 24 MB
  u16* xbf = (u16*)(ws + 25165824);     // [4096][2048], 16 MB
  u16* QKV = (u16*)(ws + 41943040);     // [4096][4096], 32 MB
  u16* Qb = (u16*)(ws + 75497472);      // [2][32][2048][64], 16 MB
  u16* Kb = (u16*)(ws + 92274688);      // [2][16][2048][64], 8 MB
  u16* Vt = (u16*)(ws + 100663296);     // [2][8][32][128][64], 8 MB
  u16* Attn = (u16*)(ws + 109051904);   // [4096][2048], 16 MB
  float* lam = (float*)(ws + 125829120);

  lam_kernel<<<1, 64, 0, stream>>>(lq1, lk1, lq2, lk2, lam);
  convert_kernel<<<8192, 256, 0, stream>>>(x, xbf, 8388608);
  transposeW_kernel<<<dim3(64, 192), 256, 0, stream>>>(Wq, Wk, Wv, Wo, WT);
  // QKV projection: 256^2 8-phase kernel (16x16 = 256 wg = 1 wg/CU)
  gemm256_kernel<<<dim3(16, 16), 512, 0, stream>>>(xbf, WT, QKV, 4096, 2048);
  // Q scale = HD^-0.5 * log2(e) so scores feed exp2 directly
  rotary_kernel<<<24576, 256, 0, stream>>>(QKV, Qb, Kb, 0.18033688011112042f);
  vtrans_kernel<<<dim3(64, 4, 16), 256, 0, stream>>>(QKV, Vt);
  // 8-wave 128-q blocks: 512 blocks (all-resident at 2/CU), complementary cost pairing
  attn_kernel<<<512, 512, 0, stream>>>(Qb, Kb, Vt, lam, g, Attn);
  // out-proj stays on 128^2 (256^2 would be 128 wg = half-idle machine)
  gemm128_kernel<false><<<dim3(16, 32), 256, 0, stream>>>(Attn, WT + (size_t)4096 * 2048, d_out,
                                                          2048, 2048);
}

// Round 7
// 350.547 us; speedup vs baseline: 1.3912x; 1.3912x over previous
//
#include <hip/hip_runtime.h>

#define T_SEQ 2048

typedef __bf16 bf16x8 __attribute__((ext_vector_type(8)));
typedef float f32x4 __attribute__((ext_vector_type(4)));
typedef unsigned short u16;

__device__ __forceinline__ u16 f2b(float f) {
  unsigned u = __float_as_uint(f);
  unsigned r = 0x7fffu + ((u >> 16) & 1u);
  return (u16)((u + r) >> 16);
}
__device__ __forceinline__ float b2f(u16 v) {
  return __uint_as_float(((unsigned)v) << 16);
}
__device__ __forceinline__ f32x4 mfma16(bf16x8 a, bf16x8 b, f32x4 c) {
  return __builtin_amdgcn_mfma_f32_16x16x32_bf16(a, b, c, 0, 0, 0);
}
// pack two f32 -> two bf16 (RTZ) in ONE v_perm_b32 (truncation ~ bf16 noise).
__device__ __forceinline__ unsigned pkhi(float lo, float hi) {
  return __builtin_amdgcn_perm(__float_as_uint(hi), __float_as_uint(lo), 0x07060302u);
}
// raw exp2 (no OCML denormal fixup; -1e30 underflows to 0 which is what we want)
#if defined(__has_builtin)
#if __has_builtin(__builtin_amdgcn_exp2f)
#define HAVE_RAW_EXP2 1
#endif
#endif
__device__ __forceinline__ float exp2r(float x) {
#ifdef HAVE_RAW_EXP2
  return __builtin_amdgcn_exp2f(x);
#else
  float r;
  asm("v_exp_f32 %0, %1" : "=v"(r) : "v"(x));
  return r;
#endif
}
// async global->LDS, 16B per lane; LDS dest = wave-uniform base + lane*16
__device__ __forceinline__ void glds16(const void* g, void* s) {
  __builtin_amdgcn_global_load_lds(
      (const __attribute__((address_space(1))) void*)(uintptr_t)g,
      (__attribute__((address_space(3))) void*)(unsigned)(uintptr_t)s, 16, 0, 0);
}

// ---------------- lambda scalar ----------------
__global__ void lam_kernel(const float* __restrict__ q1, const float* __restrict__ k1,
                           const float* __restrict__ q2, const float* __restrict__ k2,
                           float* __restrict__ outp) {
  int l = threadIdx.x;
  float a = q1[l] * k1[l];
  float c = q2[l] * k2[l];
  #pragma unroll
  for (int off = 32; off > 0; off >>= 1) {
    a += __shfl_down(a, off);
    c += __shfl_down(c, off);
  }
  if (l == 0) outp[0] = expf(a) - expf(c) + 0.7836057665316244f;  // + LAMBDA_INIT
}

// ---------------- fp32 -> bf16 convert ----------------
__global__ __launch_bounds__(256) void convert_kernel(const float* __restrict__ in,
                                                      u16* __restrict__ outp, int n) {
  int i = (blockIdx.x * 256 + threadIdx.x) * 4;
  if (i >= n) return;
  float4 v = *(const float4*)(in + i);
  ushort4 pk;
  pk.x = f2b(v.x); pk.y = f2b(v.y); pk.z = f2b(v.z); pk.w = f2b(v.w);
  *(ushort4*)(outp + i) = pk;
}

// ---------------- fused W transpose: Wq/Wk/Wv/Wo fp32 -> bf16 WT[6144][2048] ----------------
// rows 0..2048 = Wq^T, 2048..3072 = Wk^T, 3072..4096 = Wv^T, 4096..6144 = Wo^T
__global__ __launch_bounds__(256) void transposeW_kernel(const float* __restrict__ Wq,
                                                         const float* __restrict__ Wk,
                                                         const float* __restrict__ Wv,
                                                         const float* __restrict__ Wo,
                                                         u16* __restrict__ outp) {
  __shared__ float tile[32][33];
  const int ro0 = blockIdx.y * 32;  // out-row base (0..6144), never crosses a segment
  const int r0 = blockIdx.x * 32;   // source-row base (0..2048)
  const float* src; int C, cbase;
  if (ro0 < 2048)      { src = Wq; C = 2048; cbase = 0; }
  else if (ro0 < 3072) { src = Wk; C = 1024; cbase = 2048; }
  else if (ro0 < 4096) { src = Wv; C = 1024; cbase = 3072; }
  else                 { src = Wo; C = 2048; cbase = 4096; }
  const int cs0 = ro0 - cbase;
  const int tx = threadIdx.x & 31, ty = threadIdx.x >> 5;
  #pragma unroll
  for (int k2 = 0; k2 < 4; k2++)
    tile[ty * 4 + k2][tx] = src[(size_t)(r0 + ty * 4 + k2) * C + cs0 + tx];
  __syncthreads();
  #pragma unroll
  for (int k2 = 0; k2 < 4; k2++)
    outp[(size_t)(ro0 + ty * 4 + k2) * 2048 + r0 + tx] = f2b(tile[tx][ty * 4 + k2]);
}

// ---------------- m97-style GEMM: C[M][N] = A[M][K] @ BT[N][K]^T (kept for out-proj) --------
template <bool OUT_BF16>
__global__ __launch_bounds__(256) void gemm128_kernel(const u16* __restrict__ A,
                                                      const u16* __restrict__ BT,
                                                      void* __restrict__ C, int N, int K) {
  __shared__ alignas(16) u16 As[128 * 64];
  __shared__ alignas(16) u16 Bs[128 * 64];
  const int tid = threadIdx.x, w = tid >> 6, lane = tid & 63;
  const int l15 = lane & 15, quad = lane >> 4;
  const int m0 = blockIdx.y * 128, n0 = blockIdx.x * 128;
  const int wm = (w >> 1) * 64, wn = (w & 1) * 64;
  const int lr = lane >> 3, slot = lane & 7, csw = slot ^ lr;
  f32x4 acc[4][4];
  #pragma unroll
  for (int mt = 0; mt < 4; mt++)
    #pragma unroll
    for (int nt = 0; nt < 4; nt++) acc[mt][nt] = (f32x4){0.f, 0.f, 0.f, 0.f};
  const u16* Ag = A + (size_t)(m0 + w * 32 + lr) * K + csw * 8;
  const u16* Bg = BT + (size_t)(n0 + w * 32 + lr) * K + csw * 8;
  u16* Asd = As + (w * 32) * 64;
  u16* Bsd = Bs + (w * 32) * 64;
  for (int kt = 0; kt < K; kt += 64) {
    #pragma unroll
    for (int i = 0; i < 4; i++) {
      glds16(Ag + kt + (size_t)(i * 8) * K, Asd + i * 512);
      glds16(Bg + kt + (size_t)(i * 8) * K, Bsd + i * 512);
    }
    __syncthreads();
    #pragma unroll
    for (int kk = 0; kk < 2; kk++) {
      bf16x8 am[4], bn[4];
      #pragma unroll
      for (int t = 0; t < 4; t++) {
        const int ra = wm + t * 16 + l15;
        am[t] = *(const bf16x8*)&As[ra * 64 + (((kk * 4 + quad) ^ (ra & 7)) << 3)];
        const int rb = wn + t * 16 + l15;
        bn[t] = *(const bf16x8*)&Bs[rb * 64 + (((kk * 4 + quad) ^ (rb & 7)) << 3)];
      }
      #pragma unroll
      for (int mt = 0; mt < 4; mt++)
        #pragma unroll
        for (int nt = 0; nt < 4; nt++) acc[mt][nt] = mfma16(am[mt], bn[nt], acc[mt][nt]);
    }
    __syncthreads();
  }
  const int row = m0 + wm + quad * 4;
  #pragma unroll
  for (int mt = 0; mt < 4; mt++) {
    #pragma unroll
    for (int nt = 0; nt < 4; nt++) {
      const int col = n0 + wn + nt * 16 + l15;
      #pragma unroll
      for (int rr = 0; rr < 4; rr++) {
        if (OUT_BF16)
          ((u16*)C)[(size_t)(row + mt * 16 + rr) * N + col] = f2b(acc[mt][nt][rr]);
        else
          ((float*)C)[(size_t)(row + mt * 16 + rr) * N + col] = acc[mt][nt][rr];
      }
    }
  }
}

// ---------------- 256x256 8-phase GEMM (T2+T3+T4+T5): C[M][N] = A[M][K] @ BT[N][K]^T --------
// 512 thr = 8 waves (2M x 4N, 16-interleaved). BK=64, 2x double-buffered LDS (128 KiB).
// Staging runs 7 half-tiles ahead (half = 128 rows x 64, 2 glds); per tile order A0,B0,B1,A1.
// vmcnt(6) only at phases 4/8: drains to "all but last 3 halves landed" = exactly the halves
// the next tile's ds_reads need (min stage->read gap is 6 phases). Never vmcnt(0) in-loop.
// Chunk swizzle identical to gemm128 (pre-swizzled source csw = slot^lr; read ^ (row&7)).
#define STAGE_HALF(TILE, ROLE, BUF)                                                     \
  do {                                                                                  \
    const u16* sp_ = ((ROLE) == 0 || (ROLE) == 3 ? Ag : Bg) +                           \
                     (size_t)((ROLE) >= 2 ? 128 : 0) * K + (size_t)(TILE) * 64;         \
    u16* dp_ = ((ROLE) == 0 || (ROLE) == 3 ? &As[BUF][0] : &Bs[BUF][0]) +               \
               (((ROLE) >= 2 ? 128 : 0) + w * 8) * 64;                                  \
    glds16(sp_, dp_);                                                                   \
    glds16(sp_ + (size_t)64 * K, dp_ + 4096);                                           \
  } while (0)

#define PHASE(I, J, BUF, NEWA, NEWB, BN, STILE, SROLE, SBUF, DOVM)                      \
  do {                                                                                  \
    if (NEWA) {                                                                         \
      _Pragma("unroll") for (int u_ = 0; u_ < 4; u_++) {                                \
        const int ar_ = ((I) * 4 + u_) * 32 + wm * 16 + l15;                            \
        _Pragma("unroll") for (int kk_ = 0; kk_ < 2; kk_++)                             \
            am[u_][kk_] = *(const bf16x8*)&As[BUF][ar_ * 64 +                           \
                              (((kk_ * 4 + quad) ^ (ar_ & 7)) << 3)];                   \
      }                                                                                 \
    }                                                                                   \
    if (NEWB) {                                                                         \
      _Pragma("unroll") for (int v_ = 0; v_ < 2; v_++) {                                \
        const int br_ = ((J) * 2 + v_) * 64 + wn * 16 + l15;                            \
        _Pragma("unroll") for (int kk_ = 0; kk_ < 2; kk_++)                             \
            BN[v_][kk_] = *(const bf16x8*)&Bs[BUF][br_ * 64 +                           \
                              (((kk_ * 4 + quad) ^ (br_ & 7)) << 3)];                   \
      }                                                                                 \
    }                                                                                   \
    STAGE_HALF(STILE, SROLE, SBUF);                                                     \
    __builtin_amdgcn_s_barrier();                                                       \
    asm volatile("s_waitcnt lgkmcnt(0)" ::: "memory");                                  \
    __builtin_amdgcn_sched_barrier(0);                                                  \
    __builtin_amdgcn_s_setprio(1);                                                      \
    _Pragma("unroll") for (int u_ = 0; u_ < 4; u_++)                                    \
        _Pragma("unroll") for (int v_ = 0; v_ < 2; v_++) {                              \
      acc[(I) * 4 + u_][(J) * 2 + v_] =                                                 \
          mfma16(am[u_][0], BN[v_][0], acc[(I) * 4 + u_][(J) * 2 + v_]);                \
      acc[(I) * 4 + u_][(J) * 2 + v_] =                                                 \
          mfma16(am[u_][1], BN[v_][1], acc[(I) * 4 + u_][(J) * 2 + v_]);                \
    }                                                                                   \
    __builtin_amdgcn_s_setprio(0);                                                      \
    if (DOVM) asm volatile("s_waitcnt vmcnt(6)" ::: "memory");                          \
    __builtin_amdgcn_s_barrier();                                                       \
  } while (0)

__global__ __launch_bounds__(512, 2) void gemm256_kernel(const u16* __restrict__ A,
                                                         const u16* __restrict__ BT,
                                                         u16* __restrict__ C, int N, int K) {
  __shared__ alignas(16) u16 As[2][256 * 64];
  __shared__ alignas(16) u16 Bs[2][256 * 64];
  const int tid = threadIdx.x, w = tid >> 6, lane = tid & 63;
  const int l15 = lane & 15, quad = lane >> 4;
  const int wm = w >> 2, wn = w & 3;
  const int lr = lane >> 3, slot = lane & 7, csw = slot ^ lr;
  const int m0 = blockIdx.y * 256, n0 = blockIdx.x * 256;
  const int nkt = K >> 6;  // must be even

  f32x4 acc[8][4];
  #pragma unroll
  for (int r = 0; r < 8; r++)
    #pragma unroll
    for (int s = 0; s < 4; s++) acc[r][s] = (f32x4){0.f, 0.f, 0.f, 0.f};

  const u16* Ag = A + (size_t)(m0 + w * 8 + lr) * K + csw * 8;
  const u16* Bg = BT + (size_t)(n0 + w * 8 + lr) * K + csw * 8;

  bf16x8 am[4][2], bn0[2][2], bn1[2][2];

  // prologue: tile0 (A0,B0,B1,A1) + tile1 (A0,B0,B1); land tile0, keep 3 halves in flight
  STAGE_HALF(0, 0, 0); STAGE_HALF(0, 1, 0); STAGE_HALF(0, 2, 0); STAGE_HALF(0, 3, 0);
  STAGE_HALF(1, 0, 1); STAGE_HALF(1, 1, 1); STAGE_HALF(1, 2, 1);
  asm volatile("s_waitcnt vmcnt(6)" ::: "memory");
  __builtin_amdgcn_s_barrier();

  #pragma unroll 1
  for (int t = 0; t < nkt; t += 2) {
    // tile t (buf0): quads (0,0) (0,1) (1,0) (1,1); stage g = 4t+7+k
    PHASE(0, 0, 0, 1, 1, bn0, t + 1, 3, 1, 0);
    PHASE(0, 1, 0, 0, 1, bn1, t + 2, 0, 0, 0);
    PHASE(1, 0, 0, 1, 0, bn0, t + 2, 1, 0, 0);
    PHASE(1, 1, 0, 0, 0, bn1, t + 2, 2, 0, 1);
    // tile t+1 (buf1)
    PHASE(0, 0, 1, 1, 1, bn0, t + 2, 3, 0, 0);
    PHASE(0, 1, 1, 0, 1, bn1, t + 3, 0, 1, 0);
    PHASE(1, 0, 1, 1, 0, bn0, t + 3, 1, 1, 0);
    PHASE(1, 1, 1, 0, 0, bn1, t + 3, 2, 1, 1);
    // overrun stages (last iters) hit tiles >= nkt: reads stay inside the workspace and
    // only overwrite already-consumed LDS halves -> harmless, no guard needed.
  }

  const int crow = m0 + wm * 16 + quad * 4;
  const int ccol = n0 + wn * 16 + l15;
  #pragma unroll
  for (int r = 0; r < 8; r++)
    #pragma unroll
    for (int s = 0; s < 4; s++)
      #pragma unroll
      for (int rr = 0; rr < 4; rr++)
        C[(size_t)(crow + r * 32 + rr) * N + ccol + s * 64] = f2b(acc[r][s][rr]);
}

// ---------------- merged rotary: QKV -> Qb (heads 0..31, *qscale) and Kb (heads 32..47) ------
__global__ __launch_bounds__(256) void rotary_kernel(const u16* __restrict__ qkv,
                                                     u16* __restrict__ Qb,
                                                     u16* __restrict__ Kb, float qscale) {
  int idx = blockIdx.x * 256 + threadIdx.x;
  int i = idx & 31;
  int bt = (idx >> 5) & 4095;
  int hh = idx >> 17;  // 0..47 (wave-uniform)
  int t = bt & (T_SEQ - 1), b = bt >> 11;
  bool isq = hh < 32;
  int col = isq ? hh * 64 : 2048 + (hh - 32) * 64;
  size_t inb = (size_t)bt * 4096 + col + i;
  float x1 = b2f(qkv[inb]);
  float x2 = b2f(qkv[inb + 32]);
  float invf = exp2f(-(float)i * 0.4152410118609203f);
  float ang = (float)t * invf;
  float c = cosf(ang), s = sinf(ang);
  float scale = isq ? qscale : 1.0f;
  float o1 = (x1 * c + x2 * s) * scale;
  float o2 = (x2 * c - x1 * s) * scale;
  u16* outp = isq ? (Qb + (size_t)(b * 32 + hh) * (T_SEQ * 64))
                  : (Kb + (size_t)(b * 16 + hh - 32) * (T_SEQ * 64));
  size_t ob = (size_t)t * 64 + i;
  outp[ob] = f2b(o1);
  outp[ob + 32] = f2b(o2);
}

// ---------------- V slice transpose: QKV cols [3072..4096) -> Vt[B][8][32 stile][128][64] ----
// s-axis PERMUTED inside each 64-tile so the PV B-operand (P^T fragment) is lane-local:
// logical col p = hb*32 + ((s>>2)&3)*8 + ((s>>4)&1)*4 + (s&3), hb = s>>5.
// Then MFMA k=(quad*8+i) of vf0/vf1 reads s = kk*32 + (i>>2)*16 + quad*4 + (i&3), which is
// exactly the S^T output layout p[j][rr] (s = j*16 + quad*4 + rr) -> zero cross-lane traffic.
__global__ __launch_bounds__(256) void vtrans_kernel(const u16* __restrict__ qkv,
                                                     u16* __restrict__ outp) {
  __shared__ unsigned tile[32][33];
  int bh = blockIdx.z;  // b*8+hv
  int t0 = blockIdx.x * 32, dv0 = blockIdx.y * 32;
  int tx = threadIdx.x & 31, ty = threadIdx.x >> 5;
  int bt_base = (bh >> 3) * T_SEQ;
  int col = 3072 + (bh & 7) * 128 + dv0 + tx;
  #pragma unroll
  for (int k2 = 0; k2 < 4; k2++)
    tile[ty * 4 + k2][tx] = qkv[(size_t)(bt_base + t0 + ty * 4 + k2) * 4096 + col];
  __syncthreads();
  const int stile = t0 >> 6;
  const int sold = (t0 & 63) + tx;
  const int slo = sold & 31, hb = sold >> 5;
  const int sp = hb * 32 + ((slo >> 2) & 3) * 8 + ((slo >> 4) & 1) * 4 + (slo & 3);
  #pragma unroll
  for (int k2 = 0; k2 < 4; k2++) {
    int dv = dv0 + ty * 4 + k2;
    outp[(((size_t)bh * 32 + stile) * 128 + dv) * 64 + sp] = (u16)tile[tx][ty * 4 + k2];
  }
}

// ---------------- flash diff-attention, S^T formulation, 2-phase prefetch + XCD swizzle ----
// Qb [B][32][T][64] (rotary, *HD^-.5*log2e), Kb [B][16][T][64], Vt [B][8][32][128][64 perm]
// S^T = K·Q^T (lane: q=l15, s=quad*4+rr); O^T = V^T·P^T. P stays IN REGISTERS
// (V s-axis pre-permuted in vtrans). Paired q-tiles (pr, 31-pr): 512 uniform 33-step blocks.
// R3-proven schedule: prefetch into buf^1 before compute; end-of-step __syncthreads drains.
// T1 chunked XCD swizzle: HW assigns wg d -> XCD d%8; decode orig=(d&7)*64+(d>>3) so each
// XCD gets 64 CONSECUTIVE logical blocks = 4 bh K/V streams = 3MB (fits 4MB L2; before:
// all 32 streams = 24MB thrash -> 4x HBM over-fetch). Co-resident d, d+256 -> same pr cost.
// LDS 48KB: Ps (epilogue-only) aliases Ks/Vs.
__global__ __launch_bounds__(256) void attn_kernel(const u16* __restrict__ Qb,
                                                   const u16* __restrict__ Kb,
                                                   const u16* __restrict__ Vt,
                                                   const float* __restrict__ lamp,
                                                   const float* __restrict__ g,
                                                   u16* __restrict__ attn_out) {
  __shared__ alignas(16) char smem[49152];
  u16* const Ks0 = (u16*)smem;              // [2][64*64], XOR-swizzled, double-buffered
  u16* const Vs0 = (u16*)(smem + 16384);    // [2][128*64], XOR-swizzled, double-buffered
  u16* const Psb = (u16*)smem;              // [4][16][136] epilogue-only (aliases Ks/Vs)
  const int did = blockIdx.x;               // hardware id, XCD = did % 8
  const int orig = (did & 7) * 64 + (did >> 3);  // bijective chunk decode
  const int pr = orig & 15;   // handles q-tiles pr and 31-pr (33 steps total)
  const int bh = orig >> 4;
  const int b = bh >> 4, h = bh & 15;
  const int tid = threadIdx.x, w = tid >> 6, lane = tid & 63;
  const int l15 = lane & 15, quad = lane >> 4;
  const int lr = lane >> 3, slot = lane & 7, csw = slot ^ lr;
  const float lam = lamp[0];

  // per-lane global staging bases (tile-contiguous: K tile = 4096 u16, V tile = 8192 u16)
  const u16* Kg = Kb + (size_t)(b * 16 + h) * (T_SEQ * 64) + (w * 16 + lr) * 64 + csw * 8;
  const u16* Vg = Vt + (size_t)(b * 8 + (h >> 1)) * (T_SEQ * 128) + w * 2048 + lr * 64 + csw * 8;
  u16* kd[2] = {Ks0 + w * 1024, Ks0 + 4096 + w * 1024};
  u16* vd[2] = {Vs0 + w * 2048, Vs0 + 8192 + w * 2048};

  #pragma unroll 1
  for (int half = 0; half < 2; half++) {
    const int tt = half ? 31 - pr : pr;
    const int qb = tt * 64 + w * 16;  // wave's first q row
    const int qglob = qb + l15;       // this lane's q row

    bf16x8 qf[2][2];
    #pragma unroll
    for (int e = 0; e < 2; e++)
      #pragma unroll
      for (int kk = 0; kk < 2; kk++)
        qf[e][kk] = *(const bf16x8*)&Qb[((size_t)(b * 32 + 2 * h + e) * T_SEQ + qb + l15) * 64 +
                                        kk * 32 + quad * 8];

    f32x4 o[2][8];
    float lsum[2] = {0.f, 0.f};
    #pragma unroll
    for (int e = 0; e < 2; e++)
      #pragma unroll
      for (int nt = 0; nt < 8; nt++) o[e][nt] = (f32x4){0.f, 0.f, 0.f, 0.f};

    // prologue: stage tile 0 into buf 0
    {
      glds16(Kg, kd[0]); glds16(Kg + 512, kd[0] + 512);
      glds16(Vg, vd[0]); glds16(Vg + 512, vd[0] + 512);
      glds16(Vg + 1024, vd[0] + 1024); glds16(Vg + 1536, vd[0] + 1536);
    }
    __syncthreads();

    #pragma unroll 1
    for (int st = 0; st <= tt; st++) {
      const int buf = st & 1;
      const u16* Ksb = Ks0 + buf * 4096;
      const u16* Vsb = Vs0 + buf * 8192;
      if (st < tt) {  // prefetch next tile into the other buffer (uniform branch)
        const u16* kp = Kg + (size_t)(st + 1) * 4096;
        const u16* vp = Vg + (size_t)(st + 1) * 8192;
        glds16(kp, kd[buf ^ 1]); glds16(kp + 512, kd[buf ^ 1] + 512);
        glds16(vp, vd[buf ^ 1]); glds16(vp + 512, vd[buf ^ 1] + 512);
        glds16(vp + 1024, vd[buf ^ 1] + 1024); glds16(vp + 1536, vd[buf ^ 1] + 1536);
      }

      bf16x8 kf[4][2];
      #pragma unroll
      for (int j = 0; j < 4; j++) {
        const int rk = j * 16 + l15;
        #pragma unroll
        for (int kk = 0; kk < 2; kk++)
          kf[j][kk] = *(const bf16x8*)&Ksb[rk * 64 + (((kk * 4 + quad) ^ (rk & 7)) << 3)];
      }

      bf16x8 pa[2][2];
      #pragma unroll
      for (int e = 0; e < 2; e++) {
        f32x4 sc[4];
        __builtin_amdgcn_s_setprio(1);
        #pragma unroll
        for (int j = 0; j < 4; j++) {  // S^T: lane holds s=quad*4+rr, q=l15
          f32x4 z = {0.f, 0.f, 0.f, 0.f};
          z = mfma16(kf[j][0], qf[e][0], z);
          sc[j] = mfma16(kf[j][1], qf[e][1], z);
        }
        __builtin_amdgcn_s_setprio(0);
        if (st == tt) {  // causal mask (diagonal tile only)
          #pragma unroll
          for (int j = 0; j < 4; j++) {
            int srow = st * 64 + j * 16 + quad * 4;
            #pragma unroll
            for (int rr = 0; rr < 4; rr++)
              if (srow + rr > qglob) sc[j][rr] = -1e30f;
          }
        }
        float ls = 0.f;
        union { unsigned u[8]; bf16x8 v[2]; } pk;
        #pragma unroll
        for (int j = 0; j < 4; j++) {
          #pragma unroll
          for (int rr = 0; rr < 4; rr++) {
            float p = exp2r(sc[j][rr]);  // log2e folded into Q scale
            sc[j][rr] = p;
            ls += p;
          }
          pk.u[j * 2] = pkhi(sc[j][0], sc[j][1]);
          pk.u[j * 2 + 1] = pkhi(sc[j][2], sc[j][3]);
        }
        // pa[kk][i] = p[2kk + (i>>2)][i&3]; V's s-permutation makes this the exact B-frag
        pa[e][0] = pk.v[0];
        pa[e][1] = pk.v[1];
        lsum[e] += ls;
      }
      __builtin_amdgcn_s_setprio(1);
      #pragma unroll
      for (int nt = 0; nt < 8; nt++) {  // O^T = V^T·P^T
        const int rv = nt * 16 + l15;
        bf16x8 vf0 = *(const bf16x8*)&Vsb[rv * 64 + ((quad ^ (rv & 7)) << 3)];
        bf16x8 vf1 = *(const bf16x8*)&Vsb[rv * 64 + (((4 + quad) ^ (rv & 7)) << 3)];
        o[0][nt] = mfma16(vf0, pa[0][0], o[0][nt]);
        o[0][nt] = mfma16(vf1, pa[0][1], o[0][nt]);
        o[1][nt] = mfma16(vf0, pa[1][0], o[1][nt]);
        o[1][nt] = mfma16(vf1, pa[1][1], o[1][nt]);
      }
      __builtin_amdgcn_s_setprio(0);
      // drains this step's prefetch (latency already hidden by compute) and protects buf reuse
      __syncthreads();
    }

    // lane holds O^T[d = nt*16+quad*4+rr][q = l15]; reduce sums over quads (s-dim)
    float l0 = lsum[0], l1 = lsum[1];
    l0 += __shfl_xor(l0, 16); l0 += __shfl_xor(l0, 32);
    l1 += __shfl_xor(l1, 16); l1 += __shfl_xor(l1, 32);
    const float il0 = 1.f / l0, il1 = lam / l1;
    float ssq = 0.f;
    #pragma unroll
    for (int nt = 0; nt < 8; nt++)
      #pragma unroll
      for (int rr = 0; rr < 4; rr++) {
        float v = o[0][nt][rr] * il0 - o[1][nt][rr] * il1;
        o[0][nt][rr] = v;
        ssq += v * v;
      }
    ssq += __shfl_xor(ssq, 16);
    ssq += __shfl_xor(ssq, 32);
    const float rsc = rsqrtf(ssq * (1.f / 128.f) + 1e-6f) * 0.2163942334683756f;
    // stage normalized rows to LDS (transpose back): Ps[q=l15][d = 0..127]
    // (Psb aliases Ks/Vs; all in-loop reads retired by the loop's final __syncthreads)
    #pragma unroll
    for (int nt = 0; nt < 8; nt++) {
      float4 gv = *(const float4*)&g[nt * 16 + quad * 4];
      uint2 pk;
      pk.x = (unsigned)f2b(o[0][nt][0] * rsc * gv.x) |
             ((unsigned)f2b(o[0][nt][1] * rsc * gv.y) << 16);
      pk.y = (unsigned)f2b(o[0][nt][2] * rsc * gv.z) |
             ((unsigned)f2b(o[0][nt][3] * rsc * gv.w) << 16);
      *(uint2*)&Psb[(w * 16 + l15) * 136 + nt * 16 + quad * 4] = pk;
    }
    asm volatile("s_waitcnt lgkmcnt(0)" ::: "memory");
    __builtin_amdgcn_sched_barrier(0);
    // full-coverage read-back: 4 iters x 64 lanes x 8 u16 = 2048 = 16 rows x 128 cols
    #pragma unroll
    for (int i = 0; i < 4; i++) {
      const int r = (lane >> 4) + i * 4, c = (lane & 15) * 8;
      bf16x8 ov = *(const bf16x8*)&Psb[(w * 16 + r) * 136 + c];
      *(bf16x8*)&attn_out[(size_t)(b * T_SEQ + qb + r) * 2048 + h * 128 + c] = ov;
    }
    __syncthreads();  // protect Psb (aliased over Ks/Vs) before next half re-stages
  }
}

extern "C" void kernel_launch(void* const* d_in, const int* in_sizes, int n_in, void* d_out,
                              int out_size, void* d_ws, size_t ws_size, hipStream_t stream) {
  const float* x = (const float*)d_in[0];
  const float* Wq = (const float*)d_in[1];
  const float* Wk = (const float*)d_in[2];
  const float* Wv = (const float*)d_in[3];
  const float* Wo = (const float*)d_in[4];
  const float* lq1 = (const float*)d_in[5];
  const float* lk1 = (const float*)d_in[6];
  const float* lq2 = (const float*)d_in[7];
  const float* lk2 = (const float*)d_in[8];
  const float* g = (const float*)d_in[9];

  char* ws = (char*)d_ws;
  u16* WT = (u16*)(ws);                 // [6144][2048]: WqT;WkT;WvT;WoT, 24 MB
  u16* xbf = (u16*)(ws + 25165824);     // [4096][2048], 16 MB
  u16* QKV = (u16*)(ws + 41943040);     // [4096][4096], 32 MB
  u16* Qb = (u16*)(ws + 75497472);      // [2][32][2048][64], 16 MB
  u16* Kb = (u16*)(ws + 92274688);      // [2][16][2048][64], 8 MB
  u16* Vt = (u16*)(ws + 100663296);     // [2][8][32][128][64], 8 MB
  u16* Attn = (u16*)(ws + 109051904);   // [4096][2048], 16 MB
  float* lam = (float*)(ws + 125829120);

  lam_kernel<<<1, 64, 0, stream>>>(lq1, lk1, lq2, lk2, lam);
  convert_kernel<<<8192, 256, 0, stream>>>(x, xbf, 8388608);
  transposeW_kernel<<<dim3(64, 192), 256, 0, stream>>>(Wq, Wk, Wv, Wo, WT);
  // QKV projection: 256^2 8-phase kernel (16x16 = 256 wg = 1 wg/CU)
  gemm256_kernel<<<dim3(16, 16), 512, 0, stream>>>(xbf, WT, QKV, 4096, 2048);
  // Q scale = HD^-0.5 * log2(e) so scores feed exp2 directly
  rotary_kernel<<<24576, 256, 0, stream>>>(QKV, Qb, Kb, 0.18033688011112042f);
  vtrans_kernel<<<dim3(64, 4, 16), 256, 0, stream>>>(QKV, Vt);
  // paired q-tiles, 1-D grid with chunked XCD swizzle (64 consecutive blocks per XCD)
  attn_kernel<<<512, 256, 0, stream>>>(Qb, Kb, Vt, lam, g, Attn);
  // out-proj stays on 128^2 (256^2 would be 128 wg = half-idle machine)
  gemm128_kernel<false><<<dim3(16, 32), 256, 0, stream>>>(Attn, WT + (size_t)4096 * 2048, d_out,
                                                          2048, 2048);
}

// Round 8
// 321.013 us; speedup vs baseline: 1.5192x; 1.0920x over previous
//
#include <hip/hip_runtime.h>

#define T_SEQ 2048

typedef __bf16 bf16x8 __attribute__((ext_vector_type(8)));
typedef float f32x4 __attribute__((ext_vector_type(4)));
typedef unsigned short u16;

__device__ __forceinline__ u16 f2b(float f) {
  unsigned u = __float_as_uint(f);
  unsigned r = 0x7fffu + ((u >> 16) & 1u);
  return (u16)((u + r) >> 16);
}
__device__ __forceinline__ float b2f(u16 v) {
  return __uint_as_float(((unsigned)v) << 16);
}
__device__ __forceinline__ f32x4 mfma16(bf16x8 a, bf16x8 b, f32x4 c) {
  return __builtin_amdgcn_mfma_f32_16x16x32_bf16(a, b, c, 0, 0, 0);
}
// pack two f32 -> two bf16 (RTZ) in ONE v_perm_b32 (truncation ~ bf16 noise).
__device__ __forceinline__ unsigned pkhi(float lo, float hi) {
  return __builtin_amdgcn_perm(__float_as_uint(hi), __float_as_uint(lo), 0x07060302u);
}
// raw exp2 (no OCML denormal fixup; -1e30 underflows to 0 which is what we want)
#if defined(__has_builtin)
#if __has_builtin(__builtin_amdgcn_exp2f)
#define HAVE_RAW_EXP2 1
#endif
#endif
__device__ __forceinline__ float exp2r(float x) {
#ifdef HAVE_RAW_EXP2
  return __builtin_amdgcn_exp2f(x);
#else
  float r;
  asm("v_exp_f32 %0, %1" : "=v"(r) : "v"(x));
  return r;
#endif
}
// async global->LDS, 16B per lane; LDS dest = wave-uniform base + lane*16
__device__ __forceinline__ void glds16(const void* g, void* s) {
  __builtin_amdgcn_global_load_lds(
      (const __attribute__((address_space(1))) void*)(uintptr_t)g,
      (__attribute__((address_space(3))) void*)(unsigned)(uintptr_t)s, 16, 0, 0);
}

// ---------------- lambda scalar ----------------
__global__ void lam_kernel(const float* __restrict__ q1, const float* __restrict__ k1,
                           const float* __restrict__ q2, const float* __restrict__ k2,
                           float* __restrict__ outp) {
  int l = threadIdx.x;
  float a = q1[l] * k1[l];
  float c = q2[l] * k2[l];
  #pragma unroll
  for (int off = 32; off > 0; off >>= 1) {
    a += __shfl_down(a, off);
    c += __shfl_down(c, off);
  }
  if (l == 0) outp[0] = expf(a) - expf(c) + 0.7836057665316244f;  // + LAMBDA_INIT
}

// ---------------- fp32 -> bf16 convert ----------------
__global__ __launch_bounds__(256) void convert_kernel(const float* __restrict__ in,
                                                      u16* __restrict__ outp, int n) {
  int i = (blockIdx.x * 256 + threadIdx.x) * 4;
  if (i >= n) return;
  float4 v = *(const float4*)(in + i);
  ushort4 pk;
  pk.x = f2b(v.x); pk.y = f2b(v.y); pk.z = f2b(v.z); pk.w = f2b(v.w);
  *(ushort4*)(outp + i) = pk;
}

// ---------------- fused W transpose: Wq/Wk/Wv/Wo fp32 -> bf16 WT[6144][2048] ----------------
// rows 0..2048 = Wq^T, 2048..3072 = Wk^T, 3072..4096 = Wv^T, 4096..6144 = Wo^T
__global__ __launch_bounds__(256) void transposeW_kernel(const float* __restrict__ Wq,
                                                         const float* __restrict__ Wk,
                                                         const float* __restrict__ Wv,
                                                         const float* __restrict__ Wo,
                                                         u16* __restrict__ outp) {
  __shared__ float tile[32][33];
  const int ro0 = blockIdx.y * 32;  // out-row base (0..6144), never crosses a segment
  const int r0 = blockIdx.x * 32;   // source-row base (0..2048)
  const float* src; int C, cbase;
  if (ro0 < 2048)      { src = Wq; C = 2048; cbase = 0; }
  else if (ro0 < 3072) { src = Wk; C = 1024; cbase = 2048; }
  else if (ro0 < 4096) { src = Wv; C = 1024; cbase = 3072; }
  else                 { src = Wo; C = 2048; cbase = 4096; }
  const int cs0 = ro0 - cbase;
  const int tx = threadIdx.x & 31, ty = threadIdx.x >> 5;
  #pragma unroll
  for (int k2 = 0; k2 < 4; k2++)
    tile[ty * 4 + k2][tx] = src[(size_t)(r0 + ty * 4 + k2) * C + cs0 + tx];
  __syncthreads();
  #pragma unroll
  for (int k2 = 0; k2 < 4; k2++)
    outp[(size_t)(ro0 + ty * 4 + k2) * 2048 + r0 + tx] = f2b(tile[tx][ty * 4 + k2]);
}

// ---------------- m97-style GEMM: C[M][N] = A[M][K] @ BT[N][K]^T (kept for out-proj) --------
template <bool OUT_BF16>
__global__ __launch_bounds__(256) void gemm128_kernel(const u16* __restrict__ A,
                                                      const u16* __restrict__ BT,
                                                      void* __restrict__ C, int N, int K) {
  __shared__ alignas(16) u16 As[128 * 64];
  __shared__ alignas(16) u16 Bs[128 * 64];
  const int tid = threadIdx.x, w = tid >> 6, lane = tid & 63;
  const int l15 = lane & 15, quad = lane >> 4;
  const int m0 = blockIdx.y * 128, n0 = blockIdx.x * 128;
  const int wm = (w >> 1) * 64, wn = (w & 1) * 64;
  const int lr = lane >> 3, slot = lane & 7, csw = slot ^ lr;
  f32x4 acc[4][4];
  #pragma unroll
  for (int mt = 0; mt < 4; mt++)
    #pragma unroll
    for (int nt = 0; nt < 4; nt++) acc[mt][nt] = (f32x4){0.f, 0.f, 0.f, 0.f};
  const u16* Ag = A + (size_t)(m0 + w * 32 + lr) * K + csw * 8;
  const u16* Bg = BT + (size_t)(n0 + w * 32 + lr) * K + csw * 8;
  u16* Asd = As + (w * 32) * 64;
  u16* Bsd = Bs + (w * 32) * 64;
  for (int kt = 0; kt < K; kt += 64) {
    #pragma unroll
    for (int i = 0; i < 4; i++) {
      glds16(Ag + kt + (size_t)(i * 8) * K, Asd + i * 512);
      glds16(Bg + kt + (size_t)(i * 8) * K, Bsd + i * 512);
    }
    __syncthreads();
    #pragma unroll
    for (int kk = 0; kk < 2; kk++) {
      bf16x8 am[4], bn[4];
      #pragma unroll
      for (int t = 0; t < 4; t++) {
        const int ra = wm + t * 16 + l15;
        am[t] = *(const bf16x8*)&As[ra * 64 + (((kk * 4 + quad) ^ (ra & 7)) << 3)];
        const int rb = wn + t * 16 + l15;
        bn[t] = *(const bf16x8*)&Bs[rb * 64 + (((kk * 4 + quad) ^ (rb & 7)) << 3)];
      }
      #pragma unroll
      for (int mt = 0; mt < 4; mt++)
        #pragma unroll
        for (int nt = 0; nt < 4; nt++) acc[mt][nt] = mfma16(am[mt], bn[nt], acc[mt][nt]);
    }
    __syncthreads();
  }
  const int row = m0 + wm + quad * 4;
  #pragma unroll
  for (int mt = 0; mt < 4; mt++) {
    #pragma unroll
    for (int nt = 0; nt < 4; nt++) {
      const int col = n0 + wn + nt * 16 + l15;
      #pragma unroll
      for (int rr = 0; rr < 4; rr++) {
        if (OUT_BF16)
          ((u16*)C)[(size_t)(row + mt * 16 + rr) * N + col] = f2b(acc[mt][nt][rr]);
        else
          ((float*)C)[(size_t)(row + mt * 16 + rr) * N + col] = acc[mt][nt][rr];
      }
    }
  }
}

// ---------------- 256x256 8-phase GEMM (T2+T3+T4+T5): C[M][N] = A[M][K] @ BT[N][K]^T --------
// 512 thr = 8 waves (2M x 4N, 16-interleaved). BK=64, 2x double-buffered LDS (128 KiB).
// Staging runs 7 half-tiles ahead (half = 128 rows x 64, 2 glds); per tile order A0,B0,B1,A1.
// vmcnt(6) only at phases 4/8: drains to "all but last 3 halves landed" = exactly the halves
// the next tile's ds_reads need (min stage->read gap is 6 phases). Never vmcnt(0) in-loop.
// Chunk swizzle identical to gemm128 (pre-swizzled source csw = slot^lr; read ^ (row&7)).
#define STAGE_HALF(TILE, ROLE, BUF)                                                     \
  do {                                                                                  \
    const u16* sp_ = ((ROLE) == 0 || (ROLE) == 3 ? Ag : Bg) +                           \
                     (size_t)((ROLE) >= 2 ? 128 : 0) * K + (size_t)(TILE) * 64;         \
    u16* dp_ = ((ROLE) == 0 || (ROLE) == 3 ? &As[BUF][0] : &Bs[BUF][0]) +               \
               (((ROLE) >= 2 ? 128 : 0) + w * 8) * 64;                                  \
    glds16(sp_, dp_);                                                                   \
    glds16(sp_ + (size_t)64 * K, dp_ + 4096);                                           \
  } while (0)

#define PHASE(I, J, BUF, NEWA, NEWB, BN, STILE, SROLE, SBUF, DOVM)                      \
  do {                                                                                  \
    if (NEWA) {                                                                         \
      _Pragma("unroll") for (int u_ = 0; u_ < 4; u_++) {                                \
        const int ar_ = ((I) * 4 + u_) * 32 + wm * 16 + l15;                            \
        _Pragma("unroll") for (int kk_ = 0; kk_ < 2; kk_++)                             \
            am[u_][kk_] = *(const bf16x8*)&As[BUF][ar_ * 64 +                           \
                              (((kk_ * 4 + quad) ^ (ar_ & 7)) << 3)];                   \
      }                                                                                 \
    }                                                                                   \
    if (NEWB) {                                                                         \
      _Pragma("unroll") for (int v_ = 0; v_ < 2; v_++) {                                \
        const int br_ = ((J) * 2 + v_) * 64 + wn * 16 + l15;                            \
        _Pragma("unroll") for (int kk_ = 0; kk_ < 2; kk_++)                             \
            BN[v_][kk_] = *(const bf16x8*)&Bs[BUF][br_ * 64 +                           \
                              (((kk_ * 4 + quad) ^ (br_ & 7)) << 3)];                   \
      }                                                                                 \
    }                                                                                   \
    STAGE_HALF(STILE, SROLE, SBUF);                                                     \
    __builtin_amdgcn_s_barrier();                                                       \
    asm volatile("s_waitcnt lgkmcnt(0)" ::: "memory");                                  \
    __builtin_amdgcn_sched_barrier(0);                                                  \
    __builtin_amdgcn_s_setprio(1);                                                      \
    _Pragma("unroll") for (int u_ = 0; u_ < 4; u_++)                                    \
        _Pragma("unroll") for (int v_ = 0; v_ < 2; v_++) {                              \
      acc[(I) * 4 + u_][(J) * 2 + v_] =                                                 \
          mfma16(am[u_][0], BN[v_][0], acc[(I) * 4 + u_][(J) * 2 + v_]);                \
      acc[(I) * 4 + u_][(J) * 2 + v_] =                                                 \
          mfma16(am[u_][1], BN[v_][1], acc[(I) * 4 + u_][(J) * 2 + v_]);                \
    }                                                                                   \
    __builtin_amdgcn_s_setprio(0);                                                      \
    if (DOVM) asm volatile("s_waitcnt vmcnt(6)" ::: "memory");                          \
    __builtin_amdgcn_s_barrier();                                                       \
  } while (0)

__global__ __launch_bounds__(512, 2) void gemm256_kernel(const u16* __restrict__ A,
                                                         const u16* __restrict__ BT,
                                                         u16* __restrict__ C, int N, int K) {
  __shared__ alignas(16) u16 As[2][256 * 64];
  __shared__ alignas(16) u16 Bs[2][256 * 64];
  const int tid = threadIdx.x, w = tid >> 6, lane = tid & 63;
  const int l15 = lane & 15, quad = lane >> 4;
  const int wm = w >> 2, wn = w & 3;
  const int lr = lane >> 3, slot = lane & 7, csw = slot ^ lr;
  const int m0 = blockIdx.y * 256, n0 = blockIdx.x * 256;
  const int nkt = K >> 6;  // must be even

  f32x4 acc[8][4];
  #pragma unroll
  for (int r = 0; r < 8; r++)
    #pragma unroll
    for (int s = 0; s < 4; s++) acc[r][s] = (f32x4){0.f, 0.f, 0.f, 0.f};

  const u16* Ag = A + (size_t)(m0 + w * 8 + lr) * K + csw * 8;
  const u16* Bg = BT + (size_t)(n0 + w * 8 + lr) * K + csw * 8;

  bf16x8 am[4][2], bn0[2][2], bn1[2][2];

  // prologue: tile0 (A0,B0,B1,A1) + tile1 (A0,B0,B1); land tile0, keep 3 halves in flight
  STAGE_HALF(0, 0, 0); STAGE_HALF(0, 1, 0); STAGE_HALF(0, 2, 0); STAGE_HALF(0, 3, 0);
  STAGE_HALF(1, 0, 1); STAGE_HALF(1, 1, 1); STAGE_HALF(1, 2, 1);
  asm volatile("s_waitcnt vmcnt(6)" ::: "memory");
  __builtin_amdgcn_s_barrier();

  #pragma unroll 1
  for (int t = 0; t < nkt; t += 2) {
    // tile t (buf0): quads (0,0) (0,1) (1,0) (1,1); stage g = 4t+7+k
    PHASE(0, 0, 0, 1, 1, bn0, t + 1, 3, 1, 0);
    PHASE(0, 1, 0, 0, 1, bn1, t + 2, 0, 0, 0);
    PHASE(1, 0, 0, 1, 0, bn0, t + 2, 1, 0, 0);
    PHASE(1, 1, 0, 0, 0, bn1, t + 2, 2, 0, 1);
    // tile t+1 (buf1)
    PHASE(0, 0, 1, 1, 1, bn0, t + 2, 3, 0, 0);
    PHASE(0, 1, 1, 0, 1, bn1, t + 3, 0, 1, 0);
    PHASE(1, 0, 1, 1, 0, bn0, t + 3, 1, 1, 0);
    PHASE(1, 1, 1, 0, 0, bn1, t + 3, 2, 1, 1);
    // overrun stages (last iters) hit tiles >= nkt: reads stay inside the workspace and
    // only overwrite already-consumed LDS halves -> harmless, no guard needed.
  }

  const int crow = m0 + wm * 16 + quad * 4;
  const int ccol = n0 + wn * 16 + l15;
  #pragma unroll
  for (int r = 0; r < 8; r++)
    #pragma unroll
    for (int s = 0; s < 4; s++)
      #pragma unroll
      for (int rr = 0; rr < 4; rr++)
        C[(size_t)(crow + r * 32 + rr) * N + ccol + s * 64] = f2b(acc[r][s][rr]);
}

// ---------------- rotary cos/sin table: ct/st[t][i], t<2048, i<32 (65536 sincos ONCE) -----
__global__ __launch_bounds__(256) void rotab_kernel(float* __restrict__ ct,
                                                    float* __restrict__ st) {
  int idx = blockIdx.x * 256 + threadIdx.x;  // t*32 + i
  int i = idx & 31, t = idx >> 5;
  float invf = exp2f(-(float)i * 0.4152410118609203f);
  float ang = (float)t * invf;
  ct[idx] = cosf(ang);
  st[idx] = sinf(ang);
}

// ---------------- merged rotary (table-driven, vectorized): QKV -> Qb / Kb ----------------
// Thread handles 4 consecutive i (8B ushort4 loads/stores, 16B table loads).
// idx = hh*32768 + bt*8 + i4/4; hh 0..47 (Q heads 0..31 *qscale, K heads 32..47).
__global__ __launch_bounds__(256) void rotary_kernel(const u16* __restrict__ qkv,
                                                     const float* __restrict__ ct,
                                                     const float* __restrict__ st,
                                                     u16* __restrict__ Qb,
                                                     u16* __restrict__ Kb, float qscale) {
  int idx = blockIdx.x * 256 + threadIdx.x;
  int i4 = (idx & 7) * 4;
  int bt = (idx >> 3) & 4095;
  int hh = idx >> 15;  // 0..47 (wave-uniform)
  int t = bt & (T_SEQ - 1), b = bt >> 11;
  bool isq = hh < 32;
  int col = isq ? hh * 64 : 2048 + (hh - 32) * 64;
  size_t inb = (size_t)bt * 4096 + col + i4;
  ushort4 xa = *(const ushort4*)(qkv + inb);
  ushort4 xb = *(const ushort4*)(qkv + inb + 32);
  float4 c4 = *(const float4*)(ct + t * 32 + i4);
  float4 s4 = *(const float4*)(st + t * 32 + i4);
  float scale = isq ? qscale : 1.0f;
  ushort4 o1, o2;
  {
    float x1 = b2f(xa.x), x2 = b2f(xb.x);
    o1.x = f2b((x1 * c4.x + x2 * s4.x) * scale);
    o2.x = f2b((x2 * c4.x - x1 * s4.x) * scale);
  }
  {
    float x1 = b2f(xa.y), x2 = b2f(xb.y);
    o1.y = f2b((x1 * c4.y + x2 * s4.y) * scale);
    o2.y = f2b((x2 * c4.y - x1 * s4.y) * scale);
  }
  {
    float x1 = b2f(xa.z), x2 = b2f(xb.z);
    o1.z = f2b((x1 * c4.z + x2 * s4.z) * scale);
    o2.z = f2b((x2 * c4.z - x1 * s4.z) * scale);
  }
  {
    float x1 = b2f(xa.w), x2 = b2f(xb.w);
    o1.w = f2b((x1 * c4.w + x2 * s4.w) * scale);
    o2.w = f2b((x2 * c4.w - x1 * s4.w) * scale);
  }
  u16* outp = isq ? (Qb + (size_t)(b * 32 + hh) * (T_SEQ * 64))
                  : (Kb + (size_t)(b * 16 + hh - 32) * (T_SEQ * 64));
  size_t ob = (size_t)t * 64 + i4;
  *(ushort4*)(outp + ob) = o1;
  *(ushort4*)(outp + ob + 32) = o2;
}

// ---------------- V slice transpose: QKV cols [3072..4096) -> Vt[B][8][32 stile][128][64] ----
// s-axis PERMUTED inside each 64-tile so the PV B-operand (P^T fragment) is lane-local:
// logical col p = hb*32 + ((s>>2)&3)*8 + ((s>>4)&1)*4 + (s&3), hb = s>>5.
// Then MFMA k=(quad*8+i) of vf0/vf1 reads s = kk*32 + (i>>2)*16 + quad*4 + (i&3), which is
// exactly the S^T output layout p[j][rr] (s = j*16 + quad*4 + rr) -> zero cross-lane traffic.
__global__ __launch_bounds__(256) void vtrans_kernel(const u16* __restrict__ qkv,
                                                     u16* __restrict__ outp) {
  __shared__ unsigned tile[32][33];
  int bh = blockIdx.z;  // b*8+hv
  int t0 = blockIdx.x * 32, dv0 = blockIdx.y * 32;
  int tx = threadIdx.x & 31, ty = threadIdx.x >> 5;
  int bt_base = (bh >> 3) * T_SEQ;
  int col = 3072 + (bh & 7) * 128 + dv0 + tx;
  #pragma unroll
  for (int k2 = 0; k2 < 4; k2++)
    tile[ty * 4 + k2][tx] = qkv[(size_t)(bt_base + t0 + ty * 4 + k2) * 4096 + col];
  __syncthreads();
  const int stile = t0 >> 6;
  const int sold = (t0 & 63) + tx;
  const int slo = sold & 31, hb = sold >> 5;
  const int sp = hb * 32 + ((slo >> 2) & 3) * 8 + ((slo >> 4) & 1) * 4 + (slo & 3);
  #pragma unroll
  for (int k2 = 0; k2 < 4; k2++) {
    int dv = dv0 + ty * 4 + k2;
    outp[(((size_t)bh * 32 + stile) * 128 + dv) * 64 + sp] = (u16)tile[tx][ty * 4 + k2];
  }
}

// ---------------- flash diff-attention, S^T formulation, 2-phase prefetch (R3-proven) ------
// Qb [B][32][T][64] (rotary, *HD^-.5*log2e), Kb [B][16][T][64], Vt [B][8][32][128][64 perm]
// S^T = K·Q^T (lane: q=l15, s=quad*4+rr); O^T = V^T·P^T. P stays IN REGISTERS
// (V s-axis pre-permuted in vtrans). Paired q-tiles (pr, 31-pr): 512 uniform 33-step blocks.
// Prefetch into buf^1 before compute; end-of-step __syncthreads drains (R3: 71.2us).
// R5 counted-vmcnt: neutral. R7 XCD swizzle: regressed (data is L3-fit; swizzle only
// added latency + VGPR pressure). Default grid mapping restored.
// LDS 48KB: Ps (epilogue-only) aliases Ks/Vs.
__global__ __launch_bounds__(256) void attn_kernel(const u16* __restrict__ Qb,
                                                   const u16* __restrict__ Kb,
                                                   const u16* __restrict__ Vt,
                                                   const float* __restrict__ lamp,
                                                   const float* __restrict__ g,
                                                   u16* __restrict__ attn_out) {
  __shared__ alignas(16) char smem[49152];
  u16* const Ks0 = (u16*)smem;              // [2][64*64], XOR-swizzled, double-buffered
  u16* const Vs0 = (u16*)(smem + 16384);    // [2][128*64], XOR-swizzled, double-buffered
  u16* const Psb = (u16*)smem;              // [4][16][136] epilogue-only (aliases Ks/Vs)
  const int pr = blockIdx.x;  // handles q-tiles pr and 31-pr (33 steps total)
  const int bh = blockIdx.y;
  const int b = bh >> 4, h = bh & 15;
  const int tid = threadIdx.x, w = tid >> 6, lane = tid & 63;
  const int l15 = lane & 15, quad = lane >> 4;
  const int lr = lane >> 3, slot = lane & 7, csw = slot ^ lr;
  const float lam = lamp[0];

  // per-lane global staging bases (tile-contiguous: K tile = 4096 u16, V tile = 8192 u16)
  const u16* Kg = Kb + (size_t)(b * 16 + h) * (T_SEQ * 64) + (w * 16 + lr) * 64 + csw * 8;
  const u16* Vg = Vt + (size_t)(b * 8 + (h >> 1)) * (T_SEQ * 128) + w * 2048 + lr * 64 + csw * 8;
  u16* kd[2] = {Ks0 + w * 1024, Ks0 + 4096 + w * 1024};
  u16* vd[2] = {Vs0 + w * 2048, Vs0 + 8192 + w * 2048};

  #pragma unroll 1
  for (int half = 0; half < 2; half++) {
    const int tt = half ? 31 - pr : pr;
    const int qb = tt * 64 + w * 16;  // wave's first q row
    const int qglob = qb + l15;       // this lane's q row

    bf16x8 qf[2][2];
    #pragma unroll
    for (int e = 0; e < 2; e++)
      #pragma unroll
      for (int kk = 0; kk < 2; kk++)
        qf[e][kk] = *(const bf16x8*)&Qb[((size_t)(b * 32 + 2 * h + e) * T_SEQ + qb + l15) * 64 +
                                        kk * 32 + quad * 8];

    f32x4 o[2][8];
    float lsum[2] = {0.f, 0.f};
    #pragma unroll
    for (int e = 0; e < 2; e++)
      #pragma unroll
      for (int nt = 0; nt < 8; nt++) o[e][nt] = (f32x4){0.f, 0.f, 0.f, 0.f};

    // prologue: stage tile 0 into buf 0
    {
      glds16(Kg, kd[0]); glds16(Kg + 512, kd[0] + 512);
      glds16(Vg, vd[0]); glds16(Vg + 512, vd[0] + 512);
      glds16(Vg + 1024, vd[0] + 1024); glds16(Vg + 1536, vd[0] + 1536);
    }
    __syncthreads();

    #pragma unroll 1
    for (int st = 0; st <= tt; st++) {
      const int buf = st & 1;
      const u16* Ksb = Ks0 + buf * 4096;
      const u16* Vsb = Vs0 + buf * 8192;
      if (st < tt) {  // prefetch next tile into the other buffer (uniform branch)
        const u16* kp = Kg + (size_t)(st + 1) * 4096;
        const u16* vp = Vg + (size_t)(st + 1) * 8192;
        glds16(kp, kd[buf ^ 1]); glds16(kp + 512, kd[buf ^ 1] + 512);
        glds16(vp, vd[buf ^ 1]); glds16(vp + 512, vd[buf ^ 1] + 512);
        glds16(vp + 1024, vd[buf ^ 1] + 1024); glds16(vp + 1536, vd[buf ^ 1] + 1536);
      }

      bf16x8 kf[4][2];
      #pragma unroll
      for (int j = 0; j < 4; j++) {
        const int rk = j * 16 + l15;
        #pragma unroll
        for (int kk = 0; kk < 2; kk++)
          kf[j][kk] = *(const bf16x8*)&Ksb[rk * 64 + (((kk * 4 + quad) ^ (rk & 7)) << 3)];
      }

      bf16x8 pa[2][2];
      #pragma unroll
      for (int e = 0; e < 2; e++) {
        f32x4 sc[4];
        __builtin_amdgcn_s_setprio(1);
        #pragma unroll
        for (int j = 0; j < 4; j++) {  // S^T: lane holds s=quad*4+rr, q=l15
          f32x4 z = {0.f, 0.f, 0.f, 0.f};
          z = mfma16(kf[j][0], qf[e][0], z);
          sc[j] = mfma16(kf[j][1], qf[e][1], z);
        }
        __builtin_amdgcn_s_setprio(0);
        if (st == tt) {  // causal mask (diagonal tile only)
          #pragma unroll
          for (int j = 0; j < 4; j++) {
            int srow = st * 64 + j * 16 + quad * 4;
            #pragma unroll
            for (int rr = 0; rr < 4; rr++)
              if (srow + rr > qglob) sc[j][rr] = -1e30f;
          }
        }
        float ls = 0.f;
        union { unsigned u[8]; bf16x8 v[2]; } pk;
        #pragma unroll
        for (int j = 0; j < 4; j++) {
          #pragma unroll
          for (int rr = 0; rr < 4; rr++) {
            float p = exp2r(sc[j][rr]);  // log2e folded into Q scale
            sc[j][rr] = p;
            ls += p;
          }
          pk.u[j * 2] = pkhi(sc[j][0], sc[j][1]);
          pk.u[j * 2 + 1] = pkhi(sc[j][2], sc[j][3]);
        }
        // pa[kk][i] = p[2kk + (i>>2)][i&3]; V's s-permutation makes this the exact B-frag
        pa[e][0] = pk.v[0];
        pa[e][1] = pk.v[1];
        lsum[e] += ls;
      }
      __builtin_amdgcn_s_setprio(1);
      #pragma unroll
      for (int nt = 0; nt < 8; nt++) {  // O^T = V^T·P^T
        const int rv = nt * 16 + l15;
        bf16x8 vf0 = *(const bf16x8*)&Vsb[rv * 64 + ((quad ^ (rv & 7)) << 3)];
        bf16x8 vf1 = *(const bf16x8*)&Vsb[rv * 64 + (((4 + quad) ^ (rv & 7)) << 3)];
        o[0][nt] = mfma16(vf0, pa[0][0], o[0][nt]);
        o[0][nt] = mfma16(vf1, pa[0][1], o[0][nt]);
        o[1][nt] = mfma16(vf0, pa[1][0], o[1][nt]);
        o[1][nt] = mfma16(vf1, pa[1][1], o[1][nt]);
      }
      __builtin_amdgcn_s_setprio(0);
      // drains this step's prefetch (latency already hidden by compute) and protects buf reuse
      __syncthreads();
    }

    // lane holds O^T[d = nt*16+quad*4+rr][q = l15]; reduce sums over quads (s-dim)
    float l0 = lsum[0], l1 = lsum[1];
    l0 += __shfl_xor(l0, 16); l0 += __shfl_xor(l0, 32);
    l1 += __shfl_xor(l1, 16); l1 += __shfl_xor(l1, 32);
    const float il0 = 1.f / l0, il1 = lam / l1;
    float ssq = 0.f;
    #pragma unroll
    for (int nt = 0; nt < 8; nt++)
      #pragma unroll
      for (int rr = 0; rr < 4; rr++) {
        float v = o[0][nt][rr] * il0 - o[1][nt][rr] * il1;
        o[0][nt][rr] = v;
        ssq += v * v;
      }
    ssq += __shfl_xor(ssq, 16);
    ssq += __shfl_xor(ssq, 32);
    const float rsc = rsqrtf(ssq * (1.f / 128.f) + 1e-6f) * 0.2163942334683756f;
    // stage normalized rows to LDS (transpose back): Ps[q=l15][d = 0..127]
    // (Psb aliases Ks/Vs; all in-loop reads retired by the loop's final __syncthreads)
    #pragma unroll
    for (int nt = 0; nt < 8; nt++) {
      float4 gv = *(const float4*)&g[nt * 16 + quad * 4];
      uint2 pk;
      pk.x = (unsigned)f2b(o[0][nt][0] * rsc * gv.x) |
             ((unsigned)f2b(o[0][nt][1] * rsc * gv.y) << 16);
      pk.y = (unsigned)f2b(o[0][nt][2] * rsc * gv.z) |
             ((unsigned)f2b(o[0][nt][3] * rsc * gv.w) << 16);
      *(uint2*)&Psb[(w * 16 + l15) * 136 + nt * 16 + quad * 4] = pk;
    }
    asm volatile("s_waitcnt lgkmcnt(0)" ::: "memory");
    __builtin_amdgcn_sched_barrier(0);
    // full-coverage read-back: 4 iters x 64 lanes x 8 u16 = 2048 = 16 rows x 128 cols
    #pragma unroll
    for (int i = 0; i < 4; i++) {
      const int r = (lane >> 4) + i * 4, c = (lane & 15) * 8;
      bf16x8 ov = *(const bf16x8*)&Psb[(w * 16 + r) * 136 + c];
      *(bf16x8*)&attn_out[(size_t)(b * T_SEQ + qb + r) * 2048 + h * 128 + c] = ov;
    }
    __syncthreads();  // protect Psb (aliased over Ks/Vs) before next half re-stages
  }
}

extern "C" void kernel_launch(void* const* d_in, const int* in_sizes, int n_in, void* d_out,
                              int out_size, void* d_ws, size_t ws_size, hipStream_t stream) {
  const float* x = (const float*)d_in[0];
  const float* Wq = (const float*)d_in[1];
  const float* Wk = (const float*)d_in[2];
  const float* Wv = (const float*)d_in[3];
  const float* Wo = (const float*)d_in[4];
  const float* lq1 = (const float*)d_in[5];
  const float* lk1 = (const float*)d_in[6];
  const float* lq2 = (const float*)d_in[7];
  const float* lk2 = (const float*)d_in[8];
  const float* g = (const float*)d_in[9];

  char* ws = (char*)d_ws;
  u16* WT = (u16*)(ws);                 // [6144][2048]: WqT;WkT;WvT;WoT, 24 MB
  u16* xbf = (u16*)(ws + 25165824);     // [4096][2048], 16 MB (dead after gemm256)
  u16* QKV = (u16*)(ws + 41943040);     // [4096][4096], 32 MB
  u16* Qb = (u16*)(ws + 75497472);      // [2][32][2048][64], 16 MB
  u16* Kb = (u16*)(ws + 92274688);      // [2][16][2048][64], 8 MB
  u16* Vt = (u16*)(ws + 100663296);     // [2][8][32][128][64], 8 MB
  u16* Attn = (u16*)(ws + 109051904);   // [4096][2048], 16 MB
  float* lam = (float*)(ws + 125829120);
  // cos/sin tables overlay the dead xbf region (written AFTER gemm256 consumed xbf)
  float* ct = (float*)(ws + 25165824);             // [2048][32], 256 KB
  float* st = (float*)(ws + 25165824 + 262144);    // [2048][32], 256 KB

  lam_kernel<<<1, 64, 0, stream>>>(lq1, lk1, lq2, lk2, lam);
  convert_kernel<<<8192, 256, 0, stream>>>(x, xbf, 8388608);
  transposeW_kernel<<<dim3(64, 192), 256, 0, stream>>>(Wq, Wk, Wv, Wo, WT);
  // QKV projection: 256^2 8-phase kernel (16x16 = 256 wg = 1 wg/CU)
  gemm256_kernel<<<dim3(16, 16), 512, 0, stream>>>(xbf, WT, QKV, 4096, 2048);
  // rotary table (65536 sincos once; xbf is dead now) then table-driven vectorized rotary
  rotab_kernel<<<256, 256, 0, stream>>>(ct, st);
  // Q scale = HD^-0.5 * log2(e) so scores feed exp2 directly
  rotary_kernel<<<6144, 256, 0, stream>>>(QKV, ct, st, Qb, Kb, 0.18033688011112042f);
  vtrans_kernel<<<dim3(64, 4, 16), 256, 0, stream>>>(QKV, Vt);
  // paired q-tiles (pr, 31-pr): 512 uniform 33-step blocks, 2/CU (R3-proven config)
  attn_kernel<<<dim3(16, 32), 256, 0, stream>>>(Qb, Kb, Vt, lam, g, Attn);
  // out-proj stays on 128^2 (256^2 would be 128 wg = half-idle machine)
  gemm128_kernel<false><<<dim3(16, 32), 256, 0, stream>>>(Attn, WT + (size_t)4096 * 2048, d_out,
                                                          2048, 2048);
}

// Round 9
// 313.621 us; speedup vs baseline: 1.5550x; 1.0236x over previous
//
#include <hip/hip_runtime.h>

#define T_SEQ 2048

typedef __bf16 bf16x8 __attribute__((ext_vector_type(8)));
typedef float f32x4 __attribute__((ext_vector_type(4)));
typedef unsigned short u16;

__device__ __forceinline__ u16 f2b(float f) {
  unsigned u = __float_as_uint(f);
  unsigned r = 0x7fffu + ((u >> 16) & 1u);
  return (u16)((u + r) >> 16);
}
__device__ __forceinline__ float b2f(u16 v) {
  return __uint_as_float(((unsigned)v) << 16);
}
__device__ __forceinline__ f32x4 mfma16(bf16x8 a, bf16x8 b, f32x4 c) {
  return __builtin_amdgcn_mfma_f32_16x16x32_bf16(a, b, c, 0, 0, 0);
}
// pack two f32 -> two bf16 (RTZ) in ONE v_perm_b32 (truncation ~ bf16 noise).
__device__ __forceinline__ unsigned pkhi(float lo, float hi) {
  return __builtin_amdgcn_perm(__float_as_uint(hi), __float_as_uint(lo), 0x07060302u);
}
// raw exp2 (no OCML denormal fixup; -1e30 underflows to 0 which is what we want)
#if defined(__has_builtin)
#if __has_builtin(__builtin_amdgcn_exp2f)
#define HAVE_RAW_EXP2 1
#endif
#endif
__device__ __forceinline__ float exp2r(float x) {
#ifdef HAVE_RAW_EXP2
  return __builtin_amdgcn_exp2f(x);
#else
  float r;
  asm("v_exp_f32 %0, %1" : "=v"(r) : "v"(x));
  return r;
#endif
}
// async global->LDS, 16B per lane; LDS dest = wave-uniform base + lane*16
__device__ __forceinline__ void glds16(const void* g, void* s) {
  __builtin_amdgcn_global_load_lds(
      (const __attribute__((address_space(1))) void*)(uintptr_t)g,
      (__attribute__((address_space(3))) void*)(unsigned)(uintptr_t)s, 16, 0, 0);
}

// ---------------- lambda scalar ----------------
__global__ void lam_kernel(const float* __restrict__ q1, const float* __restrict__ k1,
                           const float* __restrict__ q2, const float* __restrict__ k2,
                           float* __restrict__ outp) {
  int l = threadIdx.x;
  float a = q1[l] * k1[l];
  float c = q2[l] * k2[l];
  #pragma unroll
  for (int off = 32; off > 0; off >>= 1) {
    a += __shfl_down(a, off);
    c += __shfl_down(c, off);
  }
  if (l == 0) outp[0] = expf(a) - expf(c) + 0.7836057665316244f;  // + LAMBDA_INIT
}

// ---------------- fp32 -> bf16 convert ----------------
__global__ __launch_bounds__(256) void convert_kernel(const float* __restrict__ in,
                                                      u16* __restrict__ outp, int n) {
  int i = (blockIdx.x * 256 + threadIdx.x) * 4;
  if (i >= n) return;
  float4 v = *(const float4*)(in + i);
  ushort4 pk;
  pk.x = f2b(v.x); pk.y = f2b(v.y); pk.z = f2b(v.z); pk.w = f2b(v.w);
  *(ushort4*)(outp + i) = pk;
}

// ---------------- fused W transpose: Wq/Wk/Wv/Wo fp32 -> bf16 WT[6144][2048] ----------------
// rows 0..2048 = Wq^T, 2048..3072 = Wk^T, 3072..4096 = Wv^T, 4096..6144 = Wo^T
__global__ __launch_bounds__(256) void transposeW_kernel(const float* __restrict__ Wq,
                                                         const float* __restrict__ Wk,
                                                         const float* __restrict__ Wv,
                                                         const float* __restrict__ Wo,
                                                         u16* __restrict__ outp) {
  __shared__ float tile[32][33];
  const int ro0 = blockIdx.y * 32;  // out-row base (0..6144), never crosses a segment
  const int r0 = blockIdx.x * 32;   // source-row base (0..2048)
  const float* src; int C, cbase;
  if (ro0 < 2048)      { src = Wq; C = 2048; cbase = 0; }
  else if (ro0 < 3072) { src = Wk; C = 1024; cbase = 2048; }
  else if (ro0 < 4096) { src = Wv; C = 1024; cbase = 3072; }
  else                 { src = Wo; C = 2048; cbase = 4096; }
  const int cs0 = ro0 - cbase;
  const int tx = threadIdx.x & 31, ty = threadIdx.x >> 5;
  #pragma unroll
  for (int k2 = 0; k2 < 4; k2++)
    tile[ty * 4 + k2][tx] = src[(size_t)(r0 + ty * 4 + k2) * C + cs0 + tx];
  __syncthreads();
  #pragma unroll
  for (int k2 = 0; k2 < 4; k2++)
    outp[(size_t)(ro0 + ty * 4 + k2) * 2048 + r0 + tx] = f2b(tile[tx][ty * 4 + k2]);
}

// ---------------- 256x256 8-phase GEMM (T2+T3+T4+T5): C[M][N] = A[M][K] @ BT[N][K]^T --------
// 512 thr = 8 waves (2M x 4N, 16-interleaved). BK=64, 2x double-buffered LDS (128 KiB).
// Staging runs 7 half-tiles ahead (half = 128 rows x 64, 2 glds); per tile order A0,B0,B1,A1.
// vmcnt(6) only at phases 4/8. Staged regions are always register-cached-dead (see roles).
#define STAGE_HALF(TILE, ROLE, BUF)                                                     \
  do {                                                                                  \
    const u16* sp_ = ((ROLE) == 0 || (ROLE) == 3 ? Ag : Bg) +                           \
                     (size_t)((ROLE) >= 2 ? 128 : 0) * K + (size_t)(TILE) * 64;         \
    u16* dp_ = ((ROLE) == 0 || (ROLE) == 3 ? &As[BUF][0] : &Bs[BUF][0]) +               \
               (((ROLE) >= 2 ? 128 : 0) + w * 8) * 64;                                  \
    glds16(sp_, dp_);                                                                   \
    glds16(sp_ + (size_t)64 * K, dp_ + 4096);                                           \
  } while (0)

#define PHASE(I, J, BUF, NEWA, NEWB, BN, STILE, SROLE, SBUF, DOVM)                      \
  do {                                                                                  \
    if (NEWA) {                                                                         \
      _Pragma("unroll") for (int u_ = 0; u_ < 4; u_++) {                                \
        const int ar_ = ((I) * 4 + u_) * 32 + wm * 16 + l15;                            \
        _Pragma("unroll") for (int kk_ = 0; kk_ < 2; kk_++)                             \
            am[u_][kk_] = *(const bf16x8*)&As[BUF][ar_ * 64 +                           \
                              (((kk_ * 4 + quad) ^ (ar_ & 7)) << 3)];                   \
      }                                                                                 \
    }                                                                                   \
    if (NEWB) {                                                                         \
      _Pragma("unroll") for (int v_ = 0; v_ < 2; v_++) {                                \
        const int br_ = ((J) * 2 + v_) * 64 + wn * 16 + l15;                            \
        _Pragma("unroll") for (int kk_ = 0; kk_ < 2; kk_++)                             \
            BN[v_][kk_] = *(const bf16x8*)&Bs[BUF][br_ * 64 +                           \
                              (((kk_ * 4 + quad) ^ (br_ & 7)) << 3)];                   \
      }                                                                                 \
    }                                                                                   \
    STAGE_HALF(STILE, SROLE, SBUF);                                                     \
    __builtin_amdgcn_s_barrier();                                                       \
    asm volatile("s_waitcnt lgkmcnt(0)" ::: "memory");                                  \
    __builtin_amdgcn_sched_barrier(0);                                                  \
    __builtin_amdgcn_s_setprio(1);                                                      \
    _Pragma("unroll") for (int u_ = 0; u_ < 4; u_++)                                    \
        _Pragma("unroll") for (int v_ = 0; v_ < 2; v_++) {                              \
      acc[(I) * 4 + u_][(J) * 2 + v_] =                                                 \
          mfma16(am[u_][0], BN[v_][0], acc[(I) * 4 + u_][(J) * 2 + v_]);                \
      acc[(I) * 4 + u_][(J) * 2 + v_] =                                                 \
          mfma16(am[u_][1], BN[v_][1], acc[(I) * 4 + u_][(J) * 2 + v_]);                \
    }                                                                                   \
    __builtin_amdgcn_s_setprio(0);                                                      \
    if (DOVM) asm volatile("s_waitcnt vmcnt(6)" ::: "memory");                          \
    __builtin_amdgcn_s_barrier();                                                       \
  } while (0)

__global__ __launch_bounds__(512, 2) void gemm256_kernel(const u16* __restrict__ A,
                                                         const u16* __restrict__ BT,
                                                         u16* __restrict__ C, int N, int K) {
  __shared__ alignas(16) u16 As[2][256 * 64];
  __shared__ alignas(16) u16 Bs[2][256 * 64];
  const int tid = threadIdx.x, w = tid >> 6, lane = tid & 63;
  const int l15 = lane & 15, quad = lane >> 4;
  const int wm = w >> 2, wn = w & 3;
  const int lr = lane >> 3, slot = lane & 7, csw = slot ^ lr;
  const int m0 = blockIdx.y * 256, n0 = blockIdx.x * 256;
  const int nkt = K >> 6;  // must be even

  f32x4 acc[8][4];
  #pragma unroll
  for (int r = 0; r < 8; r++)
    #pragma unroll
    for (int s = 0; s < 4; s++) acc[r][s] = (f32x4){0.f, 0.f, 0.f, 0.f};

  const u16* Ag = A + (size_t)(m0 + w * 8 + lr) * K + csw * 8;
  const u16* Bg = BT + (size_t)(n0 + w * 8 + lr) * K + csw * 8;

  bf16x8 am[4][2], bn0[2][2], bn1[2][2];

  // prologue: tile0 (A0,B0,B1,A1) + tile1 (A0,B0,B1); land tile0, keep 3 halves in flight
  STAGE_HALF(0, 0, 0); STAGE_HALF(0, 1, 0); STAGE_HALF(0, 2, 0); STAGE_HALF(0, 3, 0);
  STAGE_HALF(1, 0, 1); STAGE_HALF(1, 1, 1); STAGE_HALF(1, 2, 1);
  asm volatile("s_waitcnt vmcnt(6)" ::: "memory");
  __builtin_amdgcn_s_barrier();

  #pragma unroll 1
  for (int t = 0; t < nkt; t += 2) {
    // tile t (buf0): quads (0,0) (0,1) (1,0) (1,1); stage g = 4t+7+k
    PHASE(0, 0, 0, 1, 1, bn0, t + 1, 3, 1, 0);
    PHASE(0, 1, 0, 0, 1, bn1, t + 2, 0, 0, 0);
    PHASE(1, 0, 0, 1, 0, bn0, t + 2, 1, 0, 0);
    PHASE(1, 1, 0, 0, 0, bn1, t + 2, 2, 0, 1);
    // tile t+1 (buf1)
    PHASE(0, 0, 1, 1, 1, bn0, t + 2, 3, 0, 0);
    PHASE(0, 1, 1, 0, 1, bn1, t + 3, 0, 1, 0);
    PHASE(1, 0, 1, 1, 0, bn0, t + 3, 1, 1, 0);
    PHASE(1, 1, 1, 0, 0, bn1, t + 3, 2, 1, 1);
    // overrun stages (last iters) hit tiles >= nkt: reads stay inside the workspace and
    // only overwrite already-consumed LDS halves -> harmless, no guard needed.
  }

  const int crow = m0 + wm * 16 + quad * 4;
  const int ccol = n0 + wn * 16 + l15;
  #pragma unroll
  for (int r = 0; r < 8; r++)
    #pragma unroll
    for (int s = 0; s < 4; s++)
      #pragma unroll
      for (int rr = 0; rr < 4; rr++)
        C[(size_t)(crow + r * 32 + rr) * N + ccol + s * 64] = f2b(acc[r][s][rr]);
}

// ---------------- 128x256 2-phase-per-tile GEMM (out-proj): C fp32 = A @ BT^T -------------
// 512 thr = 8 waves (wm = w>>2 over 2x64 rows, wn = w&3 over 16-col interleave).
// LDS 96KB: As[2][128x64] + Bs[2][256x64]. Chunks per tile: c0 = {A lo, A hi, B rows 0-63},
// c1 = {B 64-127, B 128-191, B 192-255} (3 glds each). Phase J reads B rows J*128..J*128+127
// (fc = J*2+v, br = fc*64 + wn*16 + l15) -> staged regions always register-dead:
//   P0(buf0,J0) stages (t+1).c1 -> buf1 (dead since prev P3 drained)
//   P1(buf0,J1) stages (t+2).c0 -> buf0 A (read P0) + B 0-63 (read P0)  [no overlap w/ J1 reads]
//   P2(buf1,J0) stages (t+2).c1 -> buf0 (fully dead after P1)
//   P3(buf1,J1) stages (t+3).c0 -> buf1 A + B 0-63 (read P2)
// vmcnt(3) at P1/P3 end: newer = exactly the 3 glds of the chunk staged in that phase.
#define OSTAGE(TILE, CH, BUF)                                                           \
  do {                                                                                  \
    if ((CH) == 0) {                                                                    \
      glds16(Ag + (size_t)(TILE) * 64, &As[BUF][0] + w * 512);                          \
      glds16(Ag + (size_t)64 * K + (size_t)(TILE) * 64, &As[BUF][4096] + w * 512);      \
      glds16(Bg + (size_t)(TILE) * 64, &Bs[BUF][0] + w * 512);                          \
    } else {                                                                            \
      glds16(Bg + (size_t)64 * K + (size_t)(TILE) * 64, &Bs[BUF][4096] + w * 512);      \
      glds16(Bg + (size_t)128 * K + (size_t)(TILE) * 64, &Bs[BUF][8192] + w * 512);     \
      glds16(Bg + (size_t)192 * K + (size_t)(TILE) * 64, &Bs[BUF][12288] + w * 512);    \
    }                                                                                   \
  } while (0)

#define OPHASE(BUF, J, NEWA, STILE, SCH, SBUF, DOVM)                                    \
  do {                                                                                  \
    if (NEWA) {                                                                         \
      _Pragma("unroll") for (int fr_ = 0; fr_ < 4; fr_++) {                             \
        const int ar_ = wm * 64 + fr_ * 16 + l15;                                       \
        _Pragma("unroll") for (int kk_ = 0; kk_ < 2; kk_++)                             \
            am[fr_][kk_] = *(const bf16x8*)&As[BUF][ar_ * 64 +                          \
                               (((kk_ * 4 + quad) ^ (ar_ & 7)) << 3)];                  \
      }                                                                                 \
    }                                                                                   \
    _Pragma("unroll") for (int v_ = 0; v_ < 2; v_++) {                                  \
      const int br_ = ((J) * 2 + v_) * 64 + wn * 16 + l15;                              \
      _Pragma("unroll") for (int kk_ = 0; kk_ < 2; kk_++)                               \
          bn[v_][kk_] = *(const bf16x8*)&Bs[BUF][br_ * 64 +                             \
                            (((kk_ * 4 + quad) ^ (br_ & 7)) << 3)];                     \
    }                                                                                   \
    OSTAGE(STILE, SCH, SBUF);                                                           \
    __builtin_amdgcn_s_barrier();                                                       \
    asm volatile("s_waitcnt lgkmcnt(0)" ::: "memory");                                  \
    __builtin_amdgcn_sched_barrier(0);                                                  \
    __builtin_amdgcn_s_setprio(1);                                                      \
    _Pragma("unroll") for (int fr_ = 0; fr_ < 4; fr_++)                                 \
        _Pragma("unroll") for (int v_ = 0; v_ < 2; v_++) {                              \
      acc[fr_][(J) * 2 + v_] = mfma16(am[fr_][0], bn[v_][0], acc[fr_][(J) * 2 + v_]);   \
      acc[fr_][(J) * 2 + v_] = mfma16(am[fr_][1], bn[v_][1], acc[fr_][(J) * 2 + v_]);   \
    }                                                                                   \
    __builtin_amdgcn_s_setprio(0);                                                      \
    if (DOVM) asm volatile("s_waitcnt vmcnt(3)" ::: "memory");                          \
    __builtin_amdgcn_s_barrier();                                                       \
  } while (0)

__global__ __launch_bounds__(512, 2) void gemm128x256_kernel(const u16* __restrict__ A,
                                                             const u16* __restrict__ BT,
                                                             float* __restrict__ C,
                                                             int N, int K) {
  __shared__ alignas(16) u16 As[2][128 * 64];
  __shared__ alignas(16) u16 Bs[2][256 * 64];
  const int tid = threadIdx.x, w = tid >> 6, lane = tid & 63;
  const int l15 = lane & 15, quad = lane >> 4;
  const int wm = w >> 2, wn = w & 3;
  const int lr = lane >> 3, slot = lane & 7, csw = slot ^ lr;
  const int m0 = blockIdx.y * 128, n0 = blockIdx.x * 256;
  const int nkt = K >> 6;  // must be even

  f32x4 acc[4][4];
  #pragma unroll
  for (int r = 0; r < 4; r++)
    #pragma unroll
    for (int s = 0; s < 4; s++) acc[r][s] = (f32x4){0.f, 0.f, 0.f, 0.f};

  const u16* Ag = A + (size_t)(m0 + w * 8 + lr) * K + csw * 8;
  const u16* Bg = BT + (size_t)(n0 + w * 8 + lr) * K + csw * 8;

  bf16x8 am[4][2], bn[2][2];

  // prologue: tile0 fully + tile1 c0; wait tile0 (3 newer ok)
  OSTAGE(0, 0, 0); OSTAGE(0, 1, 0); OSTAGE(1, 0, 1);
  asm volatile("s_waitcnt vmcnt(3)" ::: "memory");
  __builtin_amdgcn_s_barrier();

  #pragma unroll 1
  for (int t = 0; t < nkt; t += 2) {
    OPHASE(0, 0, 1, t + 1, 1, 1, 0);
    OPHASE(0, 1, 0, t + 2, 0, 0, 1);
    OPHASE(1, 0, 1, t + 2, 1, 0, 0);
    OPHASE(1, 1, 0, t + 3, 0, 1, 1);
    // overrun staging reads stay inside the workspace; overwritten LDS already consumed.
  }

  const int crow = m0 + wm * 64 + quad * 4;
  #pragma unroll
  for (int r = 0; r < 4; r++)
    #pragma unroll
    for (int s = 0; s < 4; s++) {
      const int col = n0 + s * 64 + wn * 16 + l15;
      #pragma unroll
      for (int rr = 0; rr < 4; rr++)
        C[(size_t)(crow + r * 16 + rr) * N + col] = acc[r][s][rr];
    }
}

// ---------------- rotary cos/sin table: ct/st[t][i], t<2048, i<32 (65536 sincos ONCE) -----
__global__ __launch_bounds__(256) void rotab_kernel(float* __restrict__ ct,
                                                    float* __restrict__ st) {
  int idx = blockIdx.x * 256 + threadIdx.x;  // t*32 + i
  int i = idx & 31, t = idx >> 5;
  float invf = exp2f(-(float)i * 0.4152410118609203f);
  float ang = (float)t * invf;
  ct[idx] = cosf(ang);
  st[idx] = sinf(ang);
}

// ---------------- merged rotary (table-driven, vectorized): QKV -> Qb / Kb ----------------
__global__ __launch_bounds__(256) void rotary_kernel(const u16* __restrict__ qkv,
                                                     const float* __restrict__ ct,
                                                     const float* __restrict__ st,
                                                     u16* __restrict__ Qb,
                                                     u16* __restrict__ Kb, float qscale) {
  int idx = blockIdx.x * 256 + threadIdx.x;
  int i4 = (idx & 7) * 4;
  int bt = (idx >> 3) & 4095;
  int hh = idx >> 15;  // 0..47 (wave-uniform)
  int t = bt & (T_SEQ - 1), b = bt >> 11;
  bool isq = hh < 32;
  int col = isq ? hh * 64 : 2048 + (hh - 32) * 64;
  size_t inb = (size_t)bt * 4096 + col + i4;
  ushort4 xa = *(const ushort4*)(qkv + inb);
  ushort4 xb = *(const ushort4*)(qkv + inb + 32);
  float4 c4 = *(const float4*)(ct + t * 32 + i4);
  float4 s4 = *(const float4*)(st + t * 32 + i4);
  float scale = isq ? qscale : 1.0f;
  ushort4 o1, o2;
  {
    float x1 = b2f(xa.x), x2 = b2f(xb.x);
    o1.x = f2b((x1 * c4.x + x2 * s4.x) * scale);
    o2.x = f2b((x2 * c4.x - x1 * s4.x) * scale);
  }
  {
    float x1 = b2f(xa.y), x2 = b2f(xb.y);
    o1.y = f2b((x1 * c4.y + x2 * s4.y) * scale);
    o2.y = f2b((x2 * c4.y - x1 * s4.y) * scale);
  }
  {
    float x1 = b2f(xa.z), x2 = b2f(xb.z);
    o1.z = f2b((x1 * c4.z + x2 * s4.z) * scale);
    o2.z = f2b((x2 * c4.z - x1 * s4.z) * scale);
  }
  {
    float x1 = b2f(xa.w), x2 = b2f(xb.w);
    o1.w = f2b((x1 * c4.w + x2 * s4.w) * scale);
    o2.w = f2b((x2 * c4.w - x1 * s4.w) * scale);
  }
  u16* outp = isq ? (Qb + (size_t)(b * 32 + hh) * (T_SEQ * 64))
                  : (Kb + (size_t)(b * 16 + hh - 32) * (T_SEQ * 64));
  size_t ob = (size_t)t * 64 + i4;
  *(ushort4*)(outp + ob) = o1;
  *(ushort4*)(outp + ob + 32) = o2;
}

// ---------------- V slice transpose: QKV cols [3072..4096) -> Vt[B][8][32 stile][128][64] ----
// s-axis PERMUTED inside each 64-tile so the PV B-operand (P^T fragment) is lane-local.
__global__ __launch_bounds__(256) void vtrans_kernel(const u16* __restrict__ qkv,
                                                     u16* __restrict__ outp) {
  __shared__ unsigned tile[32][33];
  int bh = blockIdx.z;  // b*8+hv
  int t0 = blockIdx.x * 32, dv0 = blockIdx.y * 32;
  int tx = threadIdx.x & 31, ty = threadIdx.x >> 5;
  int bt_base = (bh >> 3) * T_SEQ;
  int col = 3072 + (bh & 7) * 128 + dv0 + tx;
  #pragma unroll
  for (int k2 = 0; k2 < 4; k2++)
    tile[ty * 4 + k2][tx] = qkv[(size_t)(bt_base + t0 + ty * 4 + k2) * 4096 + col];
  __syncthreads();
  const int stile = t0 >> 6;
  const int sold = (t0 & 63) + tx;
  const int slo = sold & 31, hb = sold >> 5;
  const int sp = hb * 32 + ((slo >> 2) & 3) * 8 + ((slo >> 4) & 1) * 4 + (slo & 3);
  #pragma unroll
  for (int k2 = 0; k2 < 4; k2++) {
    int dv = dv0 + ty * 4 + k2;
    outp[(((size_t)bh * 32 + stile) * 128 + dv) * 64 + sp] = (u16)tile[tx][ty * 4 + k2];
  }
}

// ---------------- flash diff-attention, S^T formulation, 2-phase prefetch (R3-proven) ------
// Qb [B][32][T][64] (rotary, *HD^-.5*log2e), Kb [B][16][T][64], Vt [B][8][32][128][64 perm]
// S^T = K·Q^T (lane: q=l15, s=quad*4+rr); O^T = V^T·P^T. P stays IN REGISTERS.
// lsum via ones-MFMA: lacc[e] = mfma(ones16x32, pa[e][kk]) accumulates sum_s P[s][q=l15]
// (A=all-ones makes the fragment layout irrelevant) -> removes 64 VALU adds/step + the
// epilogue cross-lane reduce; denominator now sums the SAME bf16 P the numerator uses.
// LDS 48KB: Ps (epilogue-only) aliases Ks/Vs.
__global__ __launch_bounds__(256) void attn_kernel(const u16* __restrict__ Qb,
                                                   const u16* __restrict__ Kb,
                                                   const u16* __restrict__ Vt,
                                                   const float* __restrict__ lamp,
                                                   const float* __restrict__ g,
                                                   u16* __restrict__ attn_out) {
  __shared__ alignas(16) char smem[49152];
  u16* const Ks0 = (u16*)smem;              // [2][64*64], XOR-swizzled, double-buffered
  u16* const Vs0 = (u16*)(smem + 16384);    // [2][128*64], XOR-swizzled, double-buffered
  u16* const Psb = (u16*)smem;              // [4][16][136] epilogue-only (aliases Ks/Vs)
  const int pr = blockIdx.x;  // handles q-tiles pr and 31-pr (33 steps total)
  const int bh = blockIdx.y;
  const int b = bh >> 4, h = bh & 15;
  const int tid = threadIdx.x, w = tid >> 6, lane = tid & 63;
  const int l15 = lane & 15, quad = lane >> 4;
  const int lr = lane >> 3, slot = lane & 7, csw = slot ^ lr;
  const float lam = lamp[0];

  union { unsigned u[4]; bf16x8 v; } onesu;
  onesu.u[0] = 0x3F803F80u; onesu.u[1] = 0x3F803F80u;
  onesu.u[2] = 0x3F803F80u; onesu.u[3] = 0x3F803F80u;
  const bf16x8 vone = onesu.v;

  // per-lane global staging bases (tile-contiguous: K tile = 4096 u16, V tile = 8192 u16)
  const u16* Kg = Kb + (size_t)(b * 16 + h) * (T_SEQ * 64) + (w * 16 + lr) * 64 + csw * 8;
  const u16* Vg = Vt + (size_t)(b * 8 + (h >> 1)) * (T_SEQ * 128) + w * 2048 + lr * 64 + csw * 8;
  u16* kd[2] = {Ks0 + w * 1024, Ks0 + 4096 + w * 1024};
  u16* vd[2] = {Vs0 + w * 2048, Vs0 + 8192 + w * 2048};

  #pragma unroll 1
  for (int half = 0; half < 2; half++) {
    const int tt = half ? 31 - pr : pr;
    const int qb = tt * 64 + w * 16;  // wave's first q row
    const int qglob = qb + l15;       // this lane's q row

    bf16x8 qf[2][2];
    #pragma unroll
    for (int e = 0; e < 2; e++)
      #pragma unroll
      for (int kk = 0; kk < 2; kk++)
        qf[e][kk] = *(const bf16x8*)&Qb[((size_t)(b * 32 + 2 * h + e) * T_SEQ + qb + l15) * 64 +
                                        kk * 32 + quad * 8];

    f32x4 o[2][8];
    f32x4 lacc[2];
    #pragma unroll
    for (int e = 0; e < 2; e++) {
      lacc[e] = (f32x4){0.f, 0.f, 0.f, 0.f};
      #pragma unroll
      for (int nt = 0; nt < 8; nt++) o[e][nt] = (f32x4){0.f, 0.f, 0.f, 0.f};
    }

    // prologue: stage tile 0 into buf 0
    {
      glds16(Kg, kd[0]); glds16(Kg + 512, kd[0] + 512);
      glds16(Vg, vd[0]); glds16(Vg + 512, vd[0] + 512);
      glds16(Vg + 1024, vd[0] + 1024); glds16(Vg + 1536, vd[0] + 1536);
    }
    __syncthreads();

    #pragma unroll 1
    for (int st = 0; st <= tt; st++) {
      const int buf = st & 1;
      const u16* Ksb = Ks0 + buf * 4096;
      const u16* Vsb = Vs0 + buf * 8192;
      if (st < tt) {  // prefetch next tile into the other buffer (uniform branch)
        const u16* kp = Kg + (size_t)(st + 1) * 4096;
        const u16* vp = Vg + (size_t)(st + 1) * 8192;
        glds16(kp, kd[buf ^ 1]); glds16(kp + 512, kd[buf ^ 1] + 512);
        glds16(vp, vd[buf ^ 1]); glds16(vp + 512, vd[buf ^ 1] + 512);
        glds16(vp + 1024, vd[buf ^ 1] + 1024); glds16(vp + 1536, vd[buf ^ 1] + 1536);
      }

      bf16x8 kf[4][2];
      #pragma unroll
      for (int j = 0; j < 4; j++) {
        const int rk = j * 16 + l15;
        #pragma unroll
        for (int kk = 0; kk < 2; kk++)
          kf[j][kk] = *(const bf16x8*)&Ksb[rk * 64 + (((kk * 4 + quad) ^ (rk & 7)) << 3)];
      }

      bf16x8 pa[2][2];
      #pragma unroll
      for (int e = 0; e < 2; e++) {
        f32x4 sc[4];
        __builtin_amdgcn_s_setprio(1);
        #pragma unroll
        for (int j = 0; j < 4; j++) {  // S^T: lane holds s=quad*4+rr, q=l15
          f32x4 z = {0.f, 0.f, 0.f, 0.f};
          z = mfma16(kf[j][0], qf[e][0], z);
          sc[j] = mfma16(kf[j][1], qf[e][1], z);
        }
        __builtin_amdgcn_s_setprio(0);
        if (st == tt) {  // causal mask (diagonal tile only)
          #pragma unroll
          for (int j = 0; j < 4; j++) {
            int srow = st * 64 + j * 16 + quad * 4;
            #pragma unroll
            for (int rr = 0; rr < 4; rr++)
              if (srow + rr > qglob) sc[j][rr] = -1e30f;
          }
        }
        union { unsigned u[8]; bf16x8 v[2]; } pk;
        #pragma unroll
        for (int j = 0; j < 4; j++) {
          #pragma unroll
          for (int rr = 0; rr < 4; rr++) sc[j][rr] = exp2r(sc[j][rr]);  // log2e in Q scale
          pk.u[j * 2] = pkhi(sc[j][0], sc[j][1]);
          pk.u[j * 2 + 1] = pkhi(sc[j][2], sc[j][3]);
        }
        // pa[kk][i] = p[2kk + (i>>2)][i&3]; V's s-permutation makes this the exact B-frag
        pa[e][0] = pk.v[0];
        pa[e][1] = pk.v[1];
        // lsum via ones-MFMA: D[m][q] = sum_k pa[k][q], uniform over m -> no reduce needed
        lacc[e] = mfma16(vone, pa[e][0], lacc[e]);
        lacc[e] = mfma16(vone, pa[e][1], lacc[e]);
      }
      __builtin_amdgcn_s_setprio(1);
      #pragma unroll
      for (int nt = 0; nt < 8; nt++) {  // O^T = V^T·P^T
        const int rv = nt * 16 + l15;
        bf16x8 vf0 = *(const bf16x8*)&Vsb[rv * 64 + ((quad ^ (rv & 7)) << 3)];
        bf16x8 vf1 = *(const bf16x8*)&Vsb[rv * 64 + (((4 + quad) ^ (rv & 7)) << 3)];
        o[0][nt] = mfma16(vf0, pa[0][0], o[0][nt]);
        o[0][nt] = mfma16(vf1, pa[0][1], o[0][nt]);
        o[1][nt] = mfma16(vf0, pa[1][0], o[1][nt]);
        o[1][nt] = mfma16(vf1, pa[1][1], o[1][nt]);
      }
      __builtin_amdgcn_s_setprio(0);
      // drains this step's prefetch (latency already hidden by compute) and protects buf reuse
      __syncthreads();
    }

    // lane holds O^T[d = nt*16+quad*4+rr][q = l15]; lacc already full row-sums (per-lane)
    const float il0 = 1.f / lacc[0][0], il1 = lam / lacc[1][0];
    float ssq = 0.f;
    #pragma unroll
    for (int nt = 0; nt < 8; nt++)
      #pragma unroll
      for (int rr = 0; rr < 4; rr++) {
        float v = o[0][nt][rr] * il0 - o[1][nt][rr] * il1;
        o[0][nt][rr] = v;
        ssq += v * v;
      }
    ssq += __shfl_xor(ssq, 16);
    ssq += __shfl_xor(ssq, 32);
    const float rsc = rsqrtf(ssq * (1.f / 128.f) + 1e-6f) * 0.2163942334683756f;
    // stage normalized rows to LDS (transpose back): Ps[q=l15][d = 0..127]
    // (Psb aliases Ks/Vs; all in-loop reads retired by the loop's final __syncthreads)
    #pragma unroll
    for (int nt = 0; nt < 8; nt++) {
      float4 gv = *(const float4*)&g[nt * 16 + quad * 4];
      uint2 pk;
      pk.x = (unsigned)f2b(o[0][nt][0] * rsc * gv.x) |
             ((unsigned)f2b(o[0][nt][1] * rsc * gv.y) << 16);
      pk.y = (unsigned)f2b(o[0][nt][2] * rsc * gv.z) |
             ((unsigned)f2b(o[0][nt][3] * rsc * gv.w) << 16);
      *(uint2*)&Psb[(w * 16 + l15) * 136 + nt * 16 + quad * 4] = pk;
    }
    asm volatile("s_waitcnt lgkmcnt(0)" ::: "memory");
    __builtin_amdgcn_sched_barrier(0);
    // full-coverage read-back: 4 iters x 64 lanes x 8 u16 = 2048 = 16 rows x 128 cols
    #pragma unroll
    for (int i = 0; i < 4; i++) {
      const int r = (lane >> 4) + i * 4, c = (lane & 15) * 8;
      bf16x8 ov = *(const bf16x8*)&Psb[(w * 16 + r) * 136 + c];
      *(bf16x8*)&attn_out[(size_t)(b * T_SEQ + qb + r) * 2048 + h * 128 + c] = ov;
    }
    __syncthreads();  // protect Psb (aliased over Ks/Vs) before next half re-stages
  }
}

extern "C" void kernel_launch(void* const* d_in, const int* in_sizes, int n_in, void* d_out,
                              int out_size, void* d_ws, size_t ws_size, hipStream_t stream) {
  const float* x = (const float*)d_in[0];
  const float* Wq = (const float*)d_in[1];
  const float* Wk = (const float*)d_in[2];
  const float* Wv = (const float*)d_in[3];
  const float* Wo = (const float*)d_in[4];
  const float* lq1 = (const float*)d_in[5];
  const float* lk1 = (const float*)d_in[6];
  const float* lq2 = (const float*)d_in[7];
  const float* lk2 = (const float*)d_in[8];
  const float* g = (const float*)d_in[9];

  char* ws = (char*)d_ws;
  u16* WT = (u16*)(ws);                 // [6144][2048]: WqT;WkT;WvT;WoT, 24 MB
  u16* xbf = (u16*)(ws + 25165824);     // [4096][2048], 16 MB (dead after gemm256)
  u16* QKV = (u16*)(ws + 41943040);     // [4096][4096], 32 MB
  u16* Qb = (u16*)(ws + 75497472);      // [2][32][2048][64], 16 MB
  u16* Kb = (u16*)(ws + 92274688);      // [2][16][2048][64], 8 MB
  u16* Vt = (u16*)(ws + 100663296);     // [2][8][32][128][64], 8 MB
  u16* Attn = (u16*)(ws + 109051904);   // [4096][2048], 16 MB
  float* lam = (float*)(ws + 125829120);
  // cos/sin tables overlay the dead xbf region (written AFTER gemm256 consumed xbf)
  float* ct = (float*)(ws + 25165824);             // [2048][32], 256 KB
  float* st = (float*)(ws + 25165824 + 262144);    // [2048][32], 256 KB

  lam_kernel<<<1, 64, 0, stream>>>(lq1, lk1, lq2, lk2, lam);
  convert_kernel<<<8192, 256, 0, stream>>>(x, xbf, 8388608);
  transposeW_kernel<<<dim3(64, 192), 256, 0, stream>>>(Wq, Wk, Wv, Wo, WT);
  // QKV projection: 256^2 8-phase kernel (16x16 = 256 wg = 1 wg/CU)
  gemm256_kernel<<<dim3(16, 16), 512, 0, stream>>>(xbf, WT, QKV, 4096, 2048);
  // rotary table (65536 sincos once; xbf is dead now) then table-driven vectorized rotary
  rotab_kernel<<<256, 256, 0, stream>>>(ct, st);
  // Q scale = HD^-0.5 * log2(e) so scores feed exp2 directly
  rotary_kernel<<<6144, 256, 0, stream>>>(QKV, ct, st, Qb, Kb, 0.18033688011112042f);
  vtrans_kernel<<<dim3(64, 4, 16), 256, 0, stream>>>(QKV, Vt);
  // paired q-tiles (pr, 31-pr): 512 uniform 33-step blocks, 2/CU (R3-proven config)
  attn_kernel<<<dim3(16, 32), 256, 0, stream>>>(Qb, Kb, Vt, lam, g, Attn);
  // out-proj: 128x256-tile pipelined GEMM, grid (8,32) = 256 wg = 1 wg/CU (full machine)
  gemm128x256_kernel<<<dim3(8, 32), 512, 0, stream>>>(Attn, WT + (size_t)4096 * 2048,
                                                      (float*)d_out, 2048, 2048);
}